// Round 11
// baseline (982.887 us; speedup 1.0000x reference)
//
#include <hip/hip_runtime.h>
#include <math.h>

#define DIMV 384
#define NHEADV 8
#define HDV 48
#define CORR_DIMV 882
#define CORR_PAD 896
#define NFRAMESV 24
#define PPIV 96
#define NPATCHV (NFRAMESV * PPIV)        // 2304
#define ETOK (NPATCHV * NFRAMESV)        // 55296
#define MTOK 96
#define NGRP (ETOK / MTOK)               // 576

using f32x4 = __attribute__((ext_vector_type(4))) float;
using s16x8 = __attribute__((ext_vector_type(8))) short;
using u16x4 = __attribute__((ext_vector_type(4))) unsigned short;

__device__ __forceinline__ unsigned int f2bf(float x) {
    union { float f; unsigned int u; } c; c.f = x;
    unsigned int u = c.u;
    u += 0x7fffu + ((u >> 16) & 1u);   // round-to-nearest-even
    return u >> 16;
}
__device__ __forceinline__ float bf2f(unsigned short x) {
    union { unsigned int u; float f; } c; c.u = ((unsigned int)x) << 16;
    return c.f;
}

__device__ __forceinline__ void gload_lds16(const void* g, void* l) {
    __builtin_amdgcn_global_load_lds(
        (const __attribute__((address_space(1))) unsigned int*)g,
        (__attribute__((address_space(3))) unsigned int*)l, 16, 0, 0);
}

// Bijective XCD-chunked block swizzle (m204).
__device__ __forceinline__ void xcd_tile(int& colblk, int& rowblk) {
    const int nwg  = gridDim.x * gridDim.y;
    const int flat = blockIdx.y * gridDim.x + blockIdx.x;
    const int xcd  = flat & 7;
    const int base = flat >> 3;
    const int q = nwg >> 3, r = nwg & 7;
    const int nf = (xcd < r ? xcd * (q + 1) : r * (q + 1) + (xcd - r) * q) + base;
    colblk = nf % gridDim.x;
    rowblk = nf / gridDim.x;
}

// ---------------------------------------------------------------------------
// Single GEMM: round-7 measured-best K-loop (2-buf, vmcnt(4), 2 barriers/tile;
// round-10's 3-ring was neutral-to-worse — reverted).
// EPI: 0 = f32 store, 1 = bf16 relu store, 5 = bf16 store,
//      6 = bf16 in-place accumulate,
//      7 = gate-combine + fused d/w head partials (atomicAdd into hdw).
// GATHER: A row r is A[gidx[r]]; gidx[r] < 0 -> reads zrow (zeroed region).
// ---------------------------------------------------------------------------
template<int EPI, bool GATHER>
__global__ __launch_bounds__(256)
void gemm_bb(const unsigned short* __restrict__ A, int lda,
             const unsigned short* __restrict__ Wt,
             const float* __restrict__ bias,
             float* __restrict__ C,
             unsigned short* __restrict__ Cb, int ldcb, int cbofs,
             const int* __restrict__ gidx,
             const unsigned short* __restrict__ zrow, int K,
             const float* __restrict__ Wd2, const float* __restrict__ Ww2,
             float* __restrict__ hdw)
{
    int colblk, rowblk;
    xcd_tile(colblk, rowblk);
    const int row0 = rowblk * 128;
    const int col0 = colblk * 128;

    __shared__ __align__(16) unsigned short As[2 * 128 * 32];
    __shared__ __align__(16) unsigned short Bs[2 * 128 * 32];

    const int tid  = threadIdx.x;
    const int lane = tid & 63;
    const int wid  = tid >> 6;
    const int wm   = wid >> 1;
    const int wn   = wid & 1;

    const int rl = lane >> 2;
    const int cp = lane & 3;

    const unsigned short* asrc[2];
    const unsigned short* bsrc[2];
    #pragma unroll
    for (int s = 0; s < 2; ++s) {
        const int r = wid * 32 + s * 16 + rl;
        const int c = cp ^ ((r >> 1) & 3);
        long arow = row0 + r;
        if (GATHER) arow = gidx[row0 + r];
        asrc[s] = (GATHER && arow < 0) ? (zrow + c * 8)
                                       : (A + arow * (long)lda + c * 8);
        bsrc[s] = Wt + (long)(col0 + r) * K + c * 8;
    }

    f32x4 acc[4][4] = {};
    const int ntiles = K >> 5;
    const int rsel = lane & 15;
    const int kq   = lane >> 4;

    auto stage = [&](int b, int ko) {
        unsigned short* a0 = &As[b * 4096 + wid * 1024];
        unsigned short* b0 = &Bs[b * 4096 + wid * 1024];
        gload_lds16(asrc[0] + ko, a0);
        gload_lds16(asrc[1] + ko, a0 + 512);
        gload_lds16(bsrc[0] + ko, b0);
        gload_lds16(bsrc[1] + ko, b0 + 512);
    };
    auto body = [&](int b) {
        const unsigned short* Ab = &As[b * 4096];
        const unsigned short* Bf = &Bs[b * 4096];
        s16x8 a[4], w[4];
        #pragma unroll
        for (int i = 0; i < 4; ++i) {
            const int R = wm * 64 + i * 16 + rsel;
            a[i] = *(const s16x8*)&Ab[R * 32 + ((kq ^ ((R >> 1) & 3)) << 3)];
        }
        #pragma unroll
        for (int j = 0; j < 4; ++j) {
            const int R = wn * 64 + j * 16 + rsel;
            w[j] = *(const s16x8*)&Bf[R * 32 + ((kq ^ ((R >> 1) & 3)) << 3)];
        }
        #pragma unroll
        for (int i = 0; i < 4; ++i)
            #pragma unroll
            for (int j = 0; j < 4; ++j)
                acc[i][j] = __builtin_amdgcn_mfma_f32_16x16x32_bf16(a[i], w[j], acc[i][j], 0, 0, 0);
    };

    stage(0, 0);
    int cur = 0;
    for (int t = 0; t + 1 < ntiles; ++t) {
        stage(cur ^ 1, (t + 1) << 5);
        asm volatile("s_waitcnt vmcnt(4)\n\ts_barrier" ::: "memory");
        body(cur);
        asm volatile("s_barrier" ::: "memory");
        cur ^= 1;
    }
    asm volatile("s_waitcnt vmcnt(0)\n\ts_barrier" ::: "memory");
    body(cur);

    const int ccol = lane & 15;
    const int rgrp = lane >> 4;

    if (EPI == 7) {
        // gate-combine + fused head partials
        #pragma unroll
        for (int i = 0; i < 4; ++i) {
            #pragma unroll
            for (int rr = 0; rr < 4; ++rr) {
                const long row  = row0 + wm * 64 + i * 16 + rgrp * 4 + rr;
                const long orow = gidx[row];
                float p0 = 0.f, p1 = 0.f, p2 = 0.f, p3 = 0.f;
                #pragma unroll
                for (int j = 0; j < 4; ++j) {
                    const int col = col0 + wn * 64 + j * 16 + ccol;
                    const float v = acc[i][j][rr] + bias[col];
                    const float gate = 1.f / (1.f + expf(-v));
                    const float tok  = bf2f(Cb[row * (long)ldcb + col]);
                    const float msg  = bf2f(Cb[row * (long)ldcb + cbofs + col]);
                    const float o = tok + gate * msg;
                    C[orow * DIMV + col] = o;
                    const float rl_ = fmaxf(o, 0.f);
                    p0 += rl_ * Wd2[col * 2 + 0];
                    p1 += rl_ * Wd2[col * 2 + 1];
                    p2 += rl_ * Ww2[col * 2 + 0];
                    p3 += rl_ * Ww2[col * 2 + 1];
                }
                #pragma unroll
                for (int o = 8; o > 0; o >>= 1) {
                    p0 += __shfl_xor(p0, o);
                    p1 += __shfl_xor(p1, o);
                    p2 += __shfl_xor(p2, o);
                    p3 += __shfl_xor(p3, o);
                }
                if (ccol == 0) {
                    atomicAdd(&hdw[orow * 4 + 0], p0);
                    atomicAdd(&hdw[orow * 4 + 1], p1);
                    atomicAdd(&hdw[orow * 4 + 2], p2);
                    atomicAdd(&hdw[orow * 4 + 3], p3);
                }
            }
        }
        return;
    }

    #pragma unroll
    for (int i = 0; i < 4; ++i) {
        const long rbase = row0 + wm * 64 + i * 16 + rgrp * 4;
        #pragma unroll
        for (int j = 0; j < 4; ++j) {
            const int col = col0 + wn * 64 + j * 16 + ccol;
            const float bsv = bias ? bias[col] : 0.f;
            #pragma unroll
            for (int rr = 0; rr < 4; ++rr) {
                const long row = rbase + rr;
                float v = acc[i][j][rr] + bsv;
                if (EPI == 0) C[row * (long)DIMV + col] = v;
                if (EPI == 1) Cb[row * (long)ldcb + cbofs + col] = (unsigned short)f2bf(fmaxf(v, 0.f));
                if (EPI == 5) Cb[row * (long)ldcb + cbofs + col] = (unsigned short)f2bf(v);
                if (EPI == 6) { const long off = row * (long)ldcb + col;
                                Cb[off] = (unsigned short)f2bf(bf2f(Cb[off]) + v); }
            }
        }
    }
}

// ---------------------------------------------------------------------------
// corr GEMM with f32 A read (no corrconv pre-pass): A = corr f32 [E][882],
// reg-staged + converted to bf16 + ds_write (rows only 8B-aligned -> float2
// loads). W = Wc1t bf16 [384][896] via gload_lds. One barrier per K-tile;
// hand-counted vmcnt: per tile issue 8 A-loads then (after barrier) 2 W-gloads.
// Invariant at loop top: outstanding = W(t) (<=2).
//   loadA(t+1) (+8) -> vmcnt(8) [W(t) done] + lgkm + barrier
//   -> stageW(t+1) (+2) -> body(t) -> vmcnt(2) [A(t+1) regs ready] -> writeA.
// Output: EPI1 (bf16 relu store).
// ---------------------------------------------------------------------------
__global__ __launch_bounds__(256)
void gemm_f32a(const float* __restrict__ A,
               const unsigned short* __restrict__ Wt,
               const float* __restrict__ bias,
               unsigned short* __restrict__ Cb)
{
    int colblk, rowblk;
    xcd_tile(colblk, rowblk);
    const int row0 = rowblk * 128;
    const int col0 = colblk * 128;

    __shared__ __align__(16) unsigned short As[2 * 128 * 32];
    __shared__ __align__(16) unsigned short Bs[2 * 128 * 32];

    const int tid  = threadIdx.x;
    const int lane = tid & 63;
    const int wid  = tid >> 6;
    const int wm   = wid >> 1;
    const int wn   = wid & 1;

    // A staging: thread -> row ra = tid>>1, k-half = (tid&1)*16
    const int ra = tid >> 1;
    const int kh = (tid & 1) << 4;
    const float* arow = A + (long)(row0 + ra) * CORR_DIMV;

    // W staging (gemm_bb scheme)
    const int rl = lane >> 2;
    const int cp = lane & 3;
    const unsigned short* bsrc[2];
    #pragma unroll
    for (int s = 0; s < 2; ++s) {
        const int r = wid * 32 + s * 16 + rl;
        const int c = cp ^ ((r >> 1) & 3);
        bsrc[s] = Wt + (long)(col0 + r) * CORR_PAD + c * 8;
    }

    f32x4 acc[4][4] = {};
    const int ntiles = CORR_PAD >> 5;    // 28
    const int rsel = lane & 15;
    const int kq   = lane >> 4;

    float2 ar[8];

    auto loadA = [&](int t) {
        const int k0 = (t << 5) + kh;
        #pragma unroll
        for (int j = 0; j < 8; ++j) {
            const int k = k0 + j * 2;
            ar[j] = (k < CORR_DIMV) ? *(const float2*)(arow + k)
                                    : make_float2(0.f, 0.f);
        }
    };
    auto writeA = [&](int b) {
        unsigned int w[8];
        #pragma unroll
        for (int j = 0; j < 8; ++j)
            w[j] = f2bf(ar[j].x) | (f2bf(ar[j].y) << 16);
        const int cbase = kh >> 3;
        const int sw = (ra >> 1) & 3;
        unsigned short* dst = &As[b * 4096 + ra * 32];
        *(uint4*)&dst[((cbase ^ sw) << 3)]       = make_uint4(w[0], w[1], w[2], w[3]);
        *(uint4*)&dst[(((cbase + 1) ^ sw) << 3)] = make_uint4(w[4], w[5], w[6], w[7]);
    };
    auto stageW = [&](int b, int t) {
        const int ko = t << 5;
        unsigned short* b0 = &Bs[b * 4096 + wid * 1024];
        gload_lds16(bsrc[0] + ko, b0);
        gload_lds16(bsrc[1] + ko, b0 + 512);
    };
    auto body = [&](int b) {
        const unsigned short* Ab = &As[b * 4096];
        const unsigned short* Bf = &Bs[b * 4096];
        s16x8 a[4], w[4];
        #pragma unroll
        for (int i = 0; i < 4; ++i) {
            const int R = wm * 64 + i * 16 + rsel;
            a[i] = *(const s16x8*)&Ab[R * 32 + ((kq ^ ((R >> 1) & 3)) << 3)];
        }
        #pragma unroll
        for (int j = 0; j < 4; ++j) {
            const int R = wn * 64 + j * 16 + rsel;
            w[j] = *(const s16x8*)&Bf[R * 32 + ((kq ^ ((R >> 1) & 3)) << 3)];
        }
        #pragma unroll
        for (int i = 0; i < 4; ++i)
            #pragma unroll
            for (int j = 0; j < 4; ++j)
                acc[i][j] = __builtin_amdgcn_mfma_f32_16x16x32_bf16(a[i], w[j], acc[i][j], 0, 0, 0);
    };

    // prologue: A(0) regs + W(0) lds
    loadA(0);            // +8
    stageW(0, 0);        // +2  (nobody reads Bs yet; pre-barrier OK)
    asm volatile("s_waitcnt vmcnt(2)" ::: "memory");    // A(0) ready
    writeA(0);

    int cur = 0;
    for (int t = 0; t < ntiles; ++t) {
        if (t + 1 < ntiles) {
            loadA(t + 1);    // +8 (outstanding <= 2 + 8)
            asm volatile("s_waitcnt vmcnt(8) lgkmcnt(0)\n\ts_barrier" ::: "memory"); // W(t) done; A-writes visible
            stageW(cur ^ 1, t + 1);   // +2 ; safe: all waves did body(t-1)
            body(cur);
            asm volatile("s_waitcnt vmcnt(2)" ::: "memory");   // A(t+1) regs ready
            writeA(cur ^ 1);
        } else {
            asm volatile("s_waitcnt vmcnt(0) lgkmcnt(0)\n\ts_barrier" ::: "memory");
            body(cur);
        }
        cur ^= 1;
    }

    // epilogue: bf16 relu store
    const int ccol = lane & 15;
    const int rgrp = lane >> 4;
    #pragma unroll
    for (int i = 0; i < 4; ++i) {
        const long rbase = row0 + wm * 64 + i * 16 + rgrp * 4;
        #pragma unroll
        for (int j = 0; j < 4; ++j) {
            const int col = col0 + wn * 64 + j * 16 + ccol;
            const float bsv = bias[col];
            #pragma unroll
            for (int rr = 0; rr < 4; ++rr) {
                const float v = acc[i][j][rr] + bsv;
                Cb[(rbase + rr) * (long)DIMV + col] = (unsigned short)f2bf(fmaxf(v, 0.f));
            }
        }
    }
}

// ---------------------------------------------------------------------------
// Weight transpose+convert. Slot order matters: 6=Wg,7=Wf (merged N=768),
// 9=Wq,10=Wk,11=Wv (merged N=1152).
// ---------------------------------------------------------------------------
struct WPtrs13 { const float* p[13]; };

__global__ __launch_bounds__(256)
void wtrans13(WPtrs13 w, unsigned short* __restrict__ out)
{
    __shared__ float t[32][33];
    const float* W = w.p[blockIdx.z];
    unsigned short* O = out + (size_t)blockIdx.z * DIMV * DIMV;
    const int k0 = blockIdx.x * 32, n0 = blockIdx.y * 32;
    const int tx = threadIdx.x, ty = threadIdx.y;
    #pragma unroll
    for (int i = ty; i < 32; i += 8)
        t[i][tx] = W[(long)(k0 + i) * DIMV + n0 + tx];
    __syncthreads();
    #pragma unroll
    for (int i = ty; i < 32; i += 8)
        O[(long)(n0 + i) * DIMV + k0 + tx] = (unsigned short)f2bf(t[tx][i]);
}

// generic: W [krows][384] f32 -> O [384][ldo] bf16 (zero-padded k >= krows)
__global__ __launch_bounds__(256)
void wtransb(const float* __restrict__ W, unsigned short* __restrict__ O,
             int krows, int ldo)
{
    __shared__ float t[32][33];
    const int k0 = blockIdx.x * 32, n0 = blockIdx.y * 32;
    const int tx = threadIdx.x, ty = threadIdx.y;
    #pragma unroll
    for (int i = ty; i < 32; i += 8)
        t[i][tx] = (k0 + i < krows) ? W[(long)(k0 + i) * DIMV + n0 + tx] : 0.f;
    __syncthreads();
    #pragma unroll
    for (int i = ty; i < 32; i += 8)
        O[(long)(n0 + i) * ldo + k0 + tx] = (unsigned short)f2bf(t[tx][i]);
}

// concat biases + zero ZR: bqkv[1152] = bq|bk|bv ; bgf[768] = bg|bf
__global__ __launch_bounds__(256)
void biascat(const float* __restrict__ bq, const float* __restrict__ bk,
             const float* __restrict__ bv, const float* __restrict__ bg,
             const float* __restrict__ bf_, float* __restrict__ bqkv,
             float* __restrict__ bgf, unsigned int* __restrict__ zr)
{
    const int t = blockIdx.x * 256 + threadIdx.x;
    if (t < 1024) zr[t] = 0u;
    if (t < 384)       { bqkv[t] = bq[t];       bgf[t] = bg[t]; }
    else if (t < 768)  { bqkv[t] = bk[t - 384]; bgf[t] = bf_[t - 384]; }
    else if (t < 1152) { bqkv[t] = bv[t - 768]; }
}

// ---------------------------------------------------------------------------
// LayerNorm (one wave per row), bf16 out.
// MODE 0: x = bf2f(sb[row]);  MODE 1: x = s0 + s1 + bf2f(sb);
// MODE 2: x = bf2f(sb[gather]) + seg[gather/24]
// ---------------------------------------------------------------------------
template<int MODE, bool RELUB>
__global__ __launch_bounds__(256)
void ln_kernel(unsigned short* __restrict__ dstb, int ldb,
               const float* __restrict__ s0, const float* __restrict__ s1,
               const unsigned short* __restrict__ sb,
               const float* __restrict__ seg, const int* __restrict__ gather,
               const float* __restrict__ g, const float* __restrict__ b)
{
    const int wave = threadIdx.x >> 6;
    const int lane = threadIdx.x & 63;
    const long row = (long)blockIdx.x * 4 + wave;
    const long srow = (MODE == 2) ? (long)gather[row] : row;

    float x[6];
    float sum = 0.f;
    #pragma unroll
    for (int i = 0; i < 6; ++i) {
        int c = lane + i * 64;
        float v;
        if (MODE == 0) v = bf2f(sb[srow * DIMV + c]);
        if (MODE == 1) v = s0[srow * DIMV + c] + s1[srow * DIMV + c] + bf2f(sb[srow * DIMV + c]);
        if (MODE == 2) v = bf2f(sb[srow * DIMV + c]) + seg[(srow / NFRAMESV) * DIMV + c];
        x[i] = v; sum += v;
    }
    #pragma unroll
    for (int o = 32; o > 0; o >>= 1) sum += __shfl_xor(sum, o);
    float mu = sum * (1.f / DIMV);
    float vs = 0.f;
    #pragma unroll
    for (int i = 0; i < 6; ++i) { float d = x[i] - mu; vs += d * d; }
    #pragma unroll
    for (int o = 32; o > 0; o >>= 1) vs += __shfl_xor(vs, o);
    float rstd = rsqrtf(vs * (1.f / DIMV) + 1e-3f);
    #pragma unroll
    for (int i = 0; i < 6; ++i) {
        int c = lane + i * 64;
        float y = (x[i] - mu) * rstd * g[c] + b[c];
        dstb[row * (long)ldb + c] = (unsigned short)f2bf(RELUB ? fmaxf(y, 0.f) : y);
    }
}

// ---------------------------------------------------------------------------
// Segment softmax-aggregation; g/f interleaved in one [E][768] bf16 buffer.
// ---------------------------------------------------------------------------
__global__ __launch_bounds__(384)
void softagg_kernel(const unsigned short* __restrict__ gf,
                    unsigned short* __restrict__ yb)
{
    const int p = blockIdx.x;
    const int col = threadIdx.x;
    const long base = (long)p * NFRAMESV * 768 + col;
    float gv[NFRAMESV];
    float gmax = -INFINITY;
    #pragma unroll
    for (int r = 0; r < NFRAMESV; ++r) {
        gv[r] = bf2f(gf[base + (long)r * 768]);
        gmax = fmaxf(gmax, gv[r]);
    }
    float den = 0.f;
    #pragma unroll
    for (int r = 0; r < NFRAMESV; ++r) { gv[r] = expf(gv[r] - gmax); den += gv[r]; }
    float acc = 0.f;
    #pragma unroll
    for (int r = 0; r < NFRAMESV; ++r) acc += bf2f(gf[base + 384 + (long)r * 768]) * gv[r];
    yb[(long)p * DIMV + col] = (unsigned short)f2bf(acc / den);
}

// ---------------------------------------------------------------------------
// RoPE + elu+1 on q and k in place, bf16, row stride ld.
// ---------------------------------------------------------------------------
__global__ __launch_bounds__(256)
void rope_kernel(unsigned short* __restrict__ q, unsigned short* __restrict__ k,
                 int ld, const float* __restrict__ pos, const int* __restrict__ flat)
{
    const long idx = (long)blockIdx.x * 256 + threadIdx.x;
    const long e = idx / 48;
    const int rem = (int)(idx % 48);
    const int h = rem / 6, d4 = (rem % 6) * 4;
    const int tok = flat[e];
    const float* cp = pos + (long)tok * HDV;
    const float* sp = pos + (long)ETOK * HDV + (long)tok * HDV;
    const float4 c1 = *(const float4*)(cp + d4);
    const float4 c2 = *(const float4*)(cp + d4 + 24);
    const float4 s1 = *(const float4*)(sp + d4);
    const float4 s2 = *(const float4*)(sp + d4 + 24);
    const long o1 = e * ld + h * HDV + d4;
    const long o2 = o1 + 24;

    float c1a[4] = {c1.x, c1.y, c1.z, c1.w};
    float c2a[4] = {c2.x, c2.y, c2.z, c2.w};
    float s1a[4] = {s1.x, s1.y, s1.z, s1.w};
    float s2a[4] = {s2.x, s2.y, s2.z, s2.w};

    u16x4 q1 = *(const u16x4*)&q[o1];
    u16x4 q2 = *(const u16x4*)&q[o2];
    u16x4 k1 = *(const u16x4*)&k[o1];
    u16x4 k2 = *(const u16x4*)&k[o2];
    u16x4 q1o, q2o, k1o, k2o;
    #pragma unroll
    for (int i = 0; i < 4; ++i) {
        const float qa = bf2f(q1[i]), qb = bf2f(q2[i]);
        float r1 = qa * c1a[i] - qb * s1a[i];
        float r2 = qb * c2a[i] + qa * s2a[i];
        r1 = (r1 > 0.f) ? r1 + 1.f : expf(r1);
        r2 = (r2 > 0.f) ? r2 + 1.f : expf(r2);
        q1o[i] = (unsigned short)f2bf(r1);
        q2o[i] = (unsigned short)f2bf(r2);
        const float ka = bf2f(k1[i]), kb = bf2f(k2[i]);
        float t1 = ka * c1a[i] - kb * s1a[i];
        float t2 = kb * c2a[i] + ka * s2a[i];
        t1 = (t1 > 0.f) ? t1 + 1.f : expf(t1);
        t2 = (t2 > 0.f) ? t2 + 1.f : expf(t2);
        k1o[i] = (unsigned short)f2bf(t1);
        k2o[i] = (unsigned short)f2bf(t2);
    }
    *(u16x4*)&q[o1] = q1o;
    *(u16x4*)&q[o2] = q2o;
    *(u16x4*)&k[o1] = k1o;
    *(u16x4*)&k[o2] = k2o;
}

// ---------------------------------------------------------------------------
// Gated linear attention core — MFMA, one WAVE per (group n, head h), bf16 io.
// ---------------------------------------------------------------------------
__global__ __launch_bounds__(256)
void attn_kernel(const unsigned short* __restrict__ qb,
                 const unsigned short* __restrict__ kb,
                 const unsigned short* __restrict__ vb, int ld,
                 unsigned short* __restrict__ ob, int ldo)
{
    __shared__ unsigned short KVt[4][48][64];
    __shared__ float KsumS[4][48];
    __shared__ float ZlS[4][96];

    const int tid  = threadIdx.x;
    const int wid  = tid >> 6;
    const int lane = tid & 63;
    const int task = blockIdx.x * 4 + wid;
    const int n = task >> 3, h = task & 7;

    const long base  = ((long)n * MTOK) * ld + h * HDV;
    const long baseo = ((long)n * MTOK) * ldo + h * HDV;

    const int c16   = lane & 15;
    const int kq    = lane >> 4;
    const int khalf = kq * 8;

    if (lane < 48) {
        const int s = (lane & 7) << 3;
        const uint4 z = make_uint4(0u, 0u, 0u, 0u);
        *(uint4*)&KVt[wid][lane][48 ^ s] = z;
        *(uint4*)&KVt[wid][lane][56 ^ s] = z;
    }

    f32x4 kv[3][3] = {};
    float ksum_p[3] = {0.f, 0.f, 0.f};

    for (int ks = 0; ks < 3; ++ks) {
        const int l0 = ks * 32 + khalf;
        s16x8 afr[3], bfr[3];
        #pragma unroll
        for (int mf = 0; mf < 3; ++mf) {
            const int d = mf * 16 + c16;
            union { unsigned short us[8]; s16x8 v; } pk;
            float s = 0.f;
            #pragma unroll
            for (int j = 0; j < 8; ++j) {
                const unsigned short kw = kb[base + (long)(l0 + j) * ld + d];
                s += bf2f(kw);
                pk.us[j] = kw;
            }
            ksum_p[mf] += s;
            afr[mf] = pk.v;
        }
        #pragma unroll
        for (int nf = 0; nf < 3; ++nf) {
            const int dv = nf * 16 + c16;
            union { unsigned short us[8]; s16x8 v; } pk;
            #pragma unroll
            for (int j = 0; j < 8; ++j)
                pk.us[j] = vb[base + (long)(l0 + j) * ld + dv];
            bfr[nf] = pk.v;
        }
        #pragma unroll
        for (int mf = 0; mf < 3; ++mf)
            #pragma unroll
            for (int nf = 0; nf < 3; ++nf)
                kv[mf][nf] = __builtin_amdgcn_mfma_f32_16x16x32_bf16(afr[mf], bfr[nf], kv[mf][nf], 0, 0, 0);
    }

    #pragma unroll
    for (int mf = 0; mf < 3; ++mf) {
        float s = ksum_p[mf];
        s += __shfl_xor(s, 16);
        s += __shfl_xor(s, 32);
        if (kq == 0) KsumS[wid][mf * 16 + c16] = s;
    }

    #pragma unroll
    for (int mf = 0; mf < 3; ++mf) {
        #pragma unroll
        for (int nf = 0; nf < 3; ++nf) {
            const int dv = nf * 16 + c16;
            const int d0 = (mf * 16 + kq * 4) ^ ((dv & 7) << 3);
            uint2 w;
            w.x = f2bf(kv[mf][nf][0]) | (f2bf(kv[mf][nf][1]) << 16);
            w.y = f2bf(kv[mf][nf][2]) | (f2bf(kv[mf][nf][3]) << 16);
            *(uint2*)&KVt[wid][dv][d0] = w;
        }
    }

    s16x8 qf[6][2];
    const s16x8 zfrag = {0, 0, 0, 0, 0, 0, 0, 0};
    #pragma unroll
    for (int mf = 0; mf < 6; ++mf) {
        const int l = mf * 16 + c16;
        float dsum = 0.f;
        #pragma unroll
        for (int ks = 0; ks < 2; ++ks) {
            if (ks == 0 || kq < 2) {
                const int d = ks * 32 + khalf;
                union { unsigned short us[8]; s16x8 v; } pk;
                pk.v = *(const s16x8*)&qb[base + (long)l * ld + d];
                #pragma unroll
                for (int j = 0; j < 8; ++j)
                    dsum += bf2f(pk.us[j]) * KsumS[wid][d + j];
                qf[mf][ks] = pk.v;
            } else {
                qf[mf][ks] = zfrag;
            }
        }
        dsum += __shfl_xor(dsum, 16);
        dsum += __shfl_xor(dsum, 32);
        if (kq == 0) ZlS[wid][l] = 1.f / (dsum + 1e-6f);
    }

    #pragma unroll
    for (int nf = 0; nf < 3; ++nf) {
        const int dv = nf * 16 + c16;
        const int sw = (dv & 7) << 3;
        const s16x8 b0 = *(const s16x8*)&KVt[wid][dv][khalf ^ sw];
        const s16x8 b1 = *(const s16x8*)&KVt[wid][dv][(32 + khalf) ^ sw];
        #pragma unroll
        for (int mf = 0; mf < 6; ++mf) {
            f32x4 a = {};
            a = __builtin_amdgcn_mfma_f32_16x16x32_bf16(qf[mf][0], b0, a, 0, 0, 0);
            a = __builtin_amdgcn_mfma_f32_16x16x32_bf16(qf[mf][1], b1, a, 0, 0, 0);
            const int lb = mf * 16 + kq * 4;
            const long rbase = baseo + (long)lb * ldo + dv;
            #pragma unroll
            for (int rr = 0; rr < 4; ++rr) {
                const float z = ZlS[wid][lb + rr];
                ob[rbase + (long)rr * ldo] = (unsigned short)f2bf(a[rr] * z);
            }
        }
    }
}

// finish heads: d = partial + bd ; w = sigmoid(partial + bw)
__global__ __launch_bounds__(256)
void head_fin(const float* __restrict__ hdw,
              const float* __restrict__ bd, const float* __restrict__ bw,
              float* __restrict__ dout, float* __restrict__ wout)
{
    const long r = (long)blockIdx.x * 256 + threadIdx.x;
    dout[r * 2 + 0] = hdw[r * 4 + 0] + bd[0];
    dout[r * 2 + 1] = hdw[r * 4 + 1] + bd[1];
    wout[r * 2 + 0] = 1.f / (1.f + expf(-(hdw[r * 4 + 2] + bw[0])));
    wout[r * 2 + 1] = 1.f / (1.f + expf(-(hdw[r * 4 + 3] + bw[1])));
}

extern "C" void kernel_launch(void* const* d_in, const int* in_sizes, int n_in,
                              void* d_out, int out_size, void* d_ws, size_t ws_size,
                              hipStream_t stream)
{
    const float* net_in = (const float*)d_in[0];
    const float* inp    = (const float*)d_in[1];
    const float* corr   = (const float*)d_in[2];
    const float* posenc = (const float*)d_in[4];
    const int*   ix     = (const int*)d_in[8];
    const int*   jx     = (const int*)d_in[9];
    const int*   flat   = (const int*)d_in[10];

    const float* Wc1 = (const float*)d_in[11]; const float* bc1 = (const float*)d_in[12];
    const float* Wc2 = (const float*)d_in[13]; const float* bc2 = (const float*)d_in[14];
    const float* g_lnc = (const float*)d_in[15]; const float* b_lnc = (const float*)d_in[16];
    const float* Wc3 = (const float*)d_in[17]; const float* bc3 = (const float*)d_in[18];
    const float* g_norm = (const float*)d_in[19]; const float* b_norm = (const float*)d_in[20];
    const float* W1a = (const float*)d_in[21]; const float* b1a = (const float*)d_in[22];
    const float* W1b = (const float*)d_in[23]; const float* b1b = (const float*)d_in[24];
    const float* W2a = (const float*)d_in[25]; const float* b2a = (const float*)d_in[26];
    const float* W2b = (const float*)d_in[27]; const float* b2b = (const float*)d_in[28];
    const float* Wf = (const float*)d_in[29]; const float* bff = (const float*)d_in[30];
    const float* Wg = (const float*)d_in[31]; const float* bg = (const float*)d_in[32];
    const float* Wh = (const float*)d_in[33]; const float* bh = (const float*)d_in[34];
    const float* g_norm2 = (const float*)d_in[35]; const float* b_norm2 = (const float*)d_in[36];
    const float* Wq = (const float*)d_in[37]; const float* bq = (const float*)d_in[38];
    const float* Wk = (const float*)d_in[39]; const float* bk = (const float*)d_in[40];
    const float* Wv = (const float*)d_in[41]; const float* bv = (const float*)d_in[42];
    const float* Wm = (const float*)d_in[43]; const float* bm = (const float*)d_in[44];
    const float* Wgt = (const float*)d_in[45]; const float* bgt = (const float*)d_in[46];
    const float* Wd = (const float*)d_in[47]; const float* bd = (const float*)d_in[48];
    const float* Ww = (const float*)d_in[49]; const float* bw = (const float*)d_in[50];

    // ---- workspace layout ----
    const size_t EB  = (size_t)ETOK * DIMV;
    const size_t WSLOT = (size_t)DIMV * DIMV;
    char* p = (char*)d_ws;
    float* Y2f = (float*)p;           p += (size_t)NPATCHV * DIMV * 4;
    unsigned short* WT = (unsigned short*)p;
    p += (13 * WSLOT + (size_t)DIMV * CORR_PAD + (size_t)DIMV * 768) * 2;
    unsigned short* ZR  = (unsigned short*)p; p += 4096;
    float* bqkv = (float*)p;          p += 1152 * 4;
    float* bgf  = (float*)p;          p += 768 * 4;
    unsigned short* Cb0 = (unsigned short*)p; p += EB * 2;
    unsigned short* Bb  = (unsigned short*)p; p += EB * 2;
    unsigned short* Xb1 = (unsigned short*)p; p += EB * 2;
    unsigned short* Xb2 = (unsigned short*)p; p += EB * 2;
    unsigned short* Xgf = (unsigned short*)p; p += (size_t)ETOK * 768 * 2;
    unsigned short* TM  = (unsigned short*)p; p += (size_t)ETOK * 768 * 2;
    unsigned short* Yb  = (unsigned short*)p; p += (size_t)NPATCHV * DIMV * 2;
    unsigned short* QKV = (unsigned short*)p; p += (size_t)ETOK * 1152 * 2;
    float* hdw = (float*)p;           p += (size_t)ETOK * 4 * 4;

    unsigned short* Wc2t = WT + 0 * WSLOT;
    unsigned short* Wc3t = WT + 1 * WSLOT;
    unsigned short* W1at = WT + 2 * WSLOT;
    unsigned short* W1bt = WT + 3 * WSLOT;
    unsigned short* W2at = WT + 4 * WSLOT;
    unsigned short* W2bt = WT + 5 * WSLOT;
    unsigned short* WgfT = WT + 6 * WSLOT;   // [768][384]: Wg | Wf
    unsigned short* Wht  = WT + 8 * WSLOT;
    unsigned short* Wqkv = WT + 9 * WSLOT;   // [1152][384]: Wq | Wk | Wv
    unsigned short* Wmt  = WT + 12 * WSLOT;
    unsigned short* Wc1t = WT + 13 * WSLOT;                 // [384][896]
    unsigned short* Wgtt = Wc1t + (size_t)DIMV * CORR_PAD;  // [384][768]

    float* out_net = (float*)d_out;
    float* out_d = out_net + EB;
    float* out_w = out_d + (size_t)ETOK * 2;

    const dim3 gB(DIMV / 128, ETOK / 128);      // (3, 432)
    const dim3 gGF(768 / 128, ETOK / 128);      // (6, 432)
    const dim3 gQKV(1152 / 128, ETOK / 128);    // (9, 432)
    const dim3 gY(DIMV / 128, NPATCHV / 128);   // (3, 18)
    const int lnBlocks = ETOK / 4;

    // ---- pre-passes ----
    {
        WPtrs13 w;
        w.p[0] = Wc2; w.p[1] = Wc3; w.p[2] = W1a; w.p[3] = W1b; w.p[4] = W2a;
        w.p[5] = W2b; w.p[6] = Wg;  w.p[7] = Wf;  w.p[8] = Wh;  w.p[9] = Wq;
        w.p[10] = Wk; w.p[11] = Wv; w.p[12] = Wm;
        wtrans13<<<dim3(12, 12, 13), dim3(32, 8), 0, stream>>>(w, WT);
        wtransb<<<dim3(28, 12), dim3(32, 8), 0, stream>>>(Wc1, Wc1t, CORR_DIMV, CORR_PAD);
        wtransb<<<dim3(24, 12), dim3(32, 8), 0, stream>>>(Wgt, Wgtt, 768, 768);
        biascat<<<5, 256, 0, stream>>>(bq, bk, bv, bg, bff, bqkv, bgf, (unsigned int*)ZR);
        hipMemsetAsync(hdw, 0, (size_t)ETOK * 4 * sizeof(float), stream);
    }

    // corr encoder: first GEMM reads corr f32 directly (no conversion pass)
    gemm_f32a<<<gB, 256, 0, stream>>>(corr, Wc1t, bc1, Cb0);
    gemm_bb<5, false><<<gB, 256, 0, stream>>>(Cb0, DIMV, Wc2t, bc2, nullptr, Xb1, DIMV, 0, nullptr, ZR, DIMV, nullptr, nullptr, nullptr);
    ln_kernel<0, true><<<lnBlocks, 256, 0, stream>>>(Cb0, DIMV, nullptr, nullptr, Xb1, nullptr, nullptr, g_lnc, b_lnc);
    gemm_bb<5, false><<<gB, 256, 0, stream>>>(Cb0, DIMV, Wc3t, bc3, nullptr, Xb2, DIMV, 0, nullptr, ZR, DIMV, nullptr, nullptr, nullptr);

    // net = LN(net + inp + c) -> Bb (bf16)
    ln_kernel<1, false><<<lnBlocks, 256, 0, stream>>>(Bb, DIMV, net_in, inp, Xb2, nullptr, nullptr, g_norm, b_norm);

    // net += mlp2(mask_ix * net[ix])
    gemm_bb<1, true><<<gB, 256, 0, stream>>>(Bb, DIMV, W1at, b1a, nullptr, Cb0, DIMV, 0, ix, ZR, DIMV, nullptr, nullptr, nullptr);
    gemm_bb<6, false><<<gB, 256, 0, stream>>>(Cb0, DIMV, W1bt, b1b, nullptr, Bb, DIMV, 0, nullptr, ZR, DIMV, nullptr, nullptr, nullptr);

    // net += mlp2(mask_jx * net[jx])
    gemm_bb<1, true><<<gB, 256, 0, stream>>>(Bb, DIMV, W2at, b2a, nullptr, Cb0, DIMV, 0, jx, ZR, DIMV, nullptr, nullptr, nullptr);
    gemm_bb<6, false><<<gB, 256, 0, stream>>>(Cb0, DIMV, W2bt, b2b, nullptr, Bb, DIMV, 0, nullptr, ZR, DIMV, nullptr, nullptr, nullptr);

    // soft aggregation: g|f in one N=768 GEMM
    gemm_bb<5, false><<<gGF, 256, 0, stream>>>(Bb, DIMV, WgfT, bgf, nullptr, Xgf, 768, 0, nullptr, ZR, DIMV, nullptr, nullptr, nullptr);
    softagg_kernel<<<NPATCHV, 384, 0, stream>>>(Xgf, Yb);
    gemm_bb<0, false><<<gY, 256, 0, stream>>>(Yb, DIMV, Wht, bh, Y2f, nullptr, DIMV, 0, nullptr, ZR, DIMV, nullptr, nullptr, nullptr);

    // tokens = LN(net[flat] + Y2[flat/24]) -> TM[:, 0:384] bf16
    ln_kernel<2, false><<<lnBlocks, 256, 0, stream>>>(TM, 768, nullptr, nullptr, Bb, Y2f, flat, g_norm2, b_norm2);

    // q|k|v in one N=1152 GEMM -> QKV [E][1152]
    gemm_bb<5, false><<<gQKV, 256, 0, stream>>>(TM, 768, Wqkv, bqkv, nullptr, QKV, 1152, 0, nullptr, ZR, DIMV, nullptr, nullptr, nullptr);

    // RoPE + elu+1 on q,k (bf16 in place)
    rope_kernel<<<(int)((long)ETOK * 48 / 256), 256, 0, stream>>>(QKV, QKV + 384, 1152, posenc, flat);

    // linear attention -> Cb0 (bf16)
    attn_kernel<<<NGRP * NHEADV / 4, 256, 0, stream>>>(QKV, QKV + 384, QKV + 768, 1152, Cb0, DIMV);

    // msg = out @ Wm + bm -> TM[:, 384:768] bf16
    gemm_bb<5, false><<<gB, 256, 0, stream>>>(Cb0, DIMV, Wmt, bm, nullptr, TM, 768, 384, nullptr, ZR, DIMV, nullptr, nullptr, nullptr);

    // gate+combine + fused head partials:
    // out_net[flat[e]] = tok + sigmoid(TM @ Wgt + bgt) * msg ; hdw += head partials
    gemm_bb<7, false><<<gB, 256, 0, stream>>>(TM, 768, Wgtt, bgt, out_net, TM, 768, 384, flat, ZR, 768, Wd, Ww, hdw);

    // finish heads
    head_fin<<<ETOK / 256, 256, 0, stream>>>(hdw, bd, bw, out_d, out_w);
}

// Round 12
// 920.160 us; speedup vs baseline: 1.0682x; 1.0682x over previous
//
#include <hip/hip_runtime.h>
#include <math.h>

#define DIMV 384
#define NHEADV 8
#define HDV 48
#define CORR_DIMV 882
#define CORR_PAD 896
#define NFRAMESV 24
#define PPIV 96
#define NPATCHV (NFRAMESV * PPIV)        // 2304
#define ETOK (NPATCHV * NFRAMESV)        // 55296
#define MTOK 96
#define NGRP (ETOK / MTOK)               // 576

using f32x4 = __attribute__((ext_vector_type(4))) float;
using s16x8 = __attribute__((ext_vector_type(8))) short;
using u16x4 = __attribute__((ext_vector_type(4))) unsigned short;

__device__ __forceinline__ unsigned int f2bf(float x) {
    union { float f; unsigned int u; } c; c.f = x;
    unsigned int u = c.u;
    u += 0x7fffu + ((u >> 16) & 1u);   // round-to-nearest-even
    return u >> 16;
}
__device__ __forceinline__ float bf2f(unsigned short x) {
    union { unsigned int u; float f; } c; c.u = ((unsigned int)x) << 16;
    return c.f;
}

__device__ __forceinline__ void gload_lds16(const void* g, void* l) {
    __builtin_amdgcn_global_load_lds(
        (const __attribute__((address_space(1))) unsigned int*)g,
        (__attribute__((address_space(3))) unsigned int*)l, 16, 0, 0);
}

// Bijective XCD-chunked block swizzle (m204).
__device__ __forceinline__ void xcd_tile(int& colblk, int& rowblk) {
    const int nwg  = gridDim.x * gridDim.y;
    const int flat = blockIdx.y * gridDim.x + blockIdx.x;
    const int xcd  = flat & 7;
    const int base = flat >> 3;
    const int q = nwg >> 3, r = nwg & 7;
    const int nf = (xcd < r ? xcd * (q + 1) : r * (q + 1) + (xcd - r) * q) + base;
    colblk = nf % gridDim.x;
    rowblk = nf / gridDim.x;
}

// ---------------------------------------------------------------------------
// Single GEMM: round-7 measured-best K-loop (2-buf, vmcnt(4), 2 barriers/tile).
// [round-11 post-mortem: reg-staged f32-A corr GEMM (gemm_f32a) was 230µs —
//  latency-bound, uncoalesced 8B row loads; corrconv+this kernel = ~127µs.
//  global_load_lds staging is the right primitive; conversion pass is cheap.]
// EPI: 0 = f32 store, 1 = bf16 relu store, 5 = bf16 store,
//      6 = bf16 in-place accumulate,
//      7 = gate-combine + fused d/w head partials (atomicAdd into hdw).
// GATHER: A row r is A[gidx[r]]; gidx[r] < 0 -> reads zrow (zeroed region).
// ---------------------------------------------------------------------------
template<int EPI, bool GATHER>
__global__ __launch_bounds__(256)
void gemm_bb(const unsigned short* __restrict__ A, int lda,
             const unsigned short* __restrict__ Wt,
             const float* __restrict__ bias,
             float* __restrict__ C,
             unsigned short* __restrict__ Cb, int ldcb, int cbofs,
             const int* __restrict__ gidx,
             const unsigned short* __restrict__ zrow, int K,
             const float* __restrict__ Wd2, const float* __restrict__ Ww2,
             float* __restrict__ hdw)
{
    int colblk, rowblk;
    xcd_tile(colblk, rowblk);
    const int row0 = rowblk * 128;
    const int col0 = colblk * 128;

    __shared__ __align__(16) unsigned short As[2 * 128 * 32];
    __shared__ __align__(16) unsigned short Bs[2 * 128 * 32];

    const int tid  = threadIdx.x;
    const int lane = tid & 63;
    const int wid  = tid >> 6;
    const int wm   = wid >> 1;
    const int wn   = wid & 1;

    const int rl = lane >> 2;
    const int cp = lane & 3;

    const unsigned short* asrc[2];
    const unsigned short* bsrc[2];
    #pragma unroll
    for (int s = 0; s < 2; ++s) {
        const int r = wid * 32 + s * 16 + rl;
        const int c = cp ^ ((r >> 1) & 3);
        long arow = row0 + r;
        if (GATHER) arow = gidx[row0 + r];
        asrc[s] = (GATHER && arow < 0) ? (zrow + c * 8)
                                       : (A + arow * (long)lda + c * 8);
        bsrc[s] = Wt + (long)(col0 + r) * K + c * 8;
    }

    f32x4 acc[4][4] = {};
    const int ntiles = K >> 5;
    const int rsel = lane & 15;
    const int kq   = lane >> 4;

    auto stage = [&](int b, int ko) {
        unsigned short* a0 = &As[b * 4096 + wid * 1024];
        unsigned short* b0 = &Bs[b * 4096 + wid * 1024];
        gload_lds16(asrc[0] + ko, a0);
        gload_lds16(asrc[1] + ko, a0 + 512);
        gload_lds16(bsrc[0] + ko, b0);
        gload_lds16(bsrc[1] + ko, b0 + 512);
    };
    auto body = [&](int b) {
        const unsigned short* Ab = &As[b * 4096];
        const unsigned short* Bf = &Bs[b * 4096];
        s16x8 a[4], w[4];
        #pragma unroll
        for (int i = 0; i < 4; ++i) {
            const int R = wm * 64 + i * 16 + rsel;
            a[i] = *(const s16x8*)&Ab[R * 32 + ((kq ^ ((R >> 1) & 3)) << 3)];
        }
        #pragma unroll
        for (int j = 0; j < 4; ++j) {
            const int R = wn * 64 + j * 16 + rsel;
            w[j] = *(const s16x8*)&Bf[R * 32 + ((kq ^ ((R >> 1) & 3)) << 3)];
        }
        #pragma unroll
        for (int i = 0; i < 4; ++i)
            #pragma unroll
            for (int j = 0; j < 4; ++j)
                acc[i][j] = __builtin_amdgcn_mfma_f32_16x16x32_bf16(a[i], w[j], acc[i][j], 0, 0, 0);
    };

    stage(0, 0);
    int cur = 0;
    for (int t = 0; t + 1 < ntiles; ++t) {
        stage(cur ^ 1, (t + 1) << 5);
        asm volatile("s_waitcnt vmcnt(4)\n\ts_barrier" ::: "memory");
        body(cur);
        asm volatile("s_barrier" ::: "memory");
        cur ^= 1;
    }
    asm volatile("s_waitcnt vmcnt(0)\n\ts_barrier" ::: "memory");
    body(cur);

    const int ccol = lane & 15;
    const int rgrp = lane >> 4;

    if (EPI == 7) {
        // gate-combine + fused head partials
        #pragma unroll
        for (int i = 0; i < 4; ++i) {
            #pragma unroll
            for (int rr = 0; rr < 4; ++rr) {
                const long row  = row0 + wm * 64 + i * 16 + rgrp * 4 + rr;
                const long orow = gidx[row];
                float p0 = 0.f, p1 = 0.f, p2 = 0.f, p3 = 0.f;
                #pragma unroll
                for (int j = 0; j < 4; ++j) {
                    const int col = col0 + wn * 64 + j * 16 + ccol;
                    const float v = acc[i][j][rr] + bias[col];
                    const float gate = 1.f / (1.f + expf(-v));
                    const float tok  = bf2f(Cb[row * (long)ldcb + col]);
                    const float msg  = bf2f(Cb[row * (long)ldcb + cbofs + col]);
                    const float o = tok + gate * msg;
                    C[orow * DIMV + col] = o;
                    const float rl_ = fmaxf(o, 0.f);
                    p0 += rl_ * Wd2[col * 2 + 0];
                    p1 += rl_ * Wd2[col * 2 + 1];
                    p2 += rl_ * Ww2[col * 2 + 0];
                    p3 += rl_ * Ww2[col * 2 + 1];
                }
                #pragma unroll
                for (int o = 8; o > 0; o >>= 1) {
                    p0 += __shfl_xor(p0, o);
                    p1 += __shfl_xor(p1, o);
                    p2 += __shfl_xor(p2, o);
                    p3 += __shfl_xor(p3, o);
                }
                if (ccol == 0) {
                    atomicAdd(&hdw[orow * 4 + 0], p0);
                    atomicAdd(&hdw[orow * 4 + 1], p1);
                    atomicAdd(&hdw[orow * 4 + 2], p2);
                    atomicAdd(&hdw[orow * 4 + 3], p3);
                }
            }
        }
        return;
    }

    #pragma unroll
    for (int i = 0; i < 4; ++i) {
        const long rbase = row0 + wm * 64 + i * 16 + rgrp * 4;
        #pragma unroll
        for (int j = 0; j < 4; ++j) {
            const int col = col0 + wn * 64 + j * 16 + ccol;
            const float bsv = bias ? bias[col] : 0.f;
            #pragma unroll
            for (int rr = 0; rr < 4; ++rr) {
                const long row = rbase + rr;
                float v = acc[i][j][rr] + bsv;
                if (EPI == 0) C[row * (long)DIMV + col] = v;
                if (EPI == 1) Cb[row * (long)ldcb + cbofs + col] = (unsigned short)f2bf(fmaxf(v, 0.f));
                if (EPI == 5) Cb[row * (long)ldcb + cbofs + col] = (unsigned short)f2bf(v);
                if (EPI == 6) { const long off = row * (long)ldcb + col;
                                Cb[off] = (unsigned short)f2bf(bf2f(Cb[off]) + v); }
            }
        }
    }
}

// ---------------------------------------------------------------------------
// Weight transpose+convert. Slot order matters: 6=Wg,7=Wf (merged N=768),
// 9=Wq,10=Wk,11=Wv (merged N=1152).
// ---------------------------------------------------------------------------
struct WPtrs13 { const float* p[13]; };

__global__ __launch_bounds__(256)
void wtrans13(WPtrs13 w, unsigned short* __restrict__ out)
{
    __shared__ float t[32][33];
    const float* W = w.p[blockIdx.z];
    unsigned short* O = out + (size_t)blockIdx.z * DIMV * DIMV;
    const int k0 = blockIdx.x * 32, n0 = blockIdx.y * 32;
    const int tx = threadIdx.x, ty = threadIdx.y;
    #pragma unroll
    for (int i = ty; i < 32; i += 8)
        t[i][tx] = W[(long)(k0 + i) * DIMV + n0 + tx];
    __syncthreads();
    #pragma unroll
    for (int i = ty; i < 32; i += 8)
        O[(long)(n0 + i) * DIMV + k0 + tx] = (unsigned short)f2bf(t[tx][i]);
}

// generic: W [krows][384] f32 -> O [384][ldo] bf16 (zero-padded k >= krows)
__global__ __launch_bounds__(256)
void wtransb(const float* __restrict__ W, unsigned short* __restrict__ O,
             int krows, int ldo)
{
    __shared__ float t[32][33];
    const int k0 = blockIdx.x * 32, n0 = blockIdx.y * 32;
    const int tx = threadIdx.x, ty = threadIdx.y;
    #pragma unroll
    for (int i = ty; i < 32; i += 8)
        t[i][tx] = (k0 + i < krows) ? W[(long)(k0 + i) * DIMV + n0 + tx] : 0.f;
    __syncthreads();
    #pragma unroll
    for (int i = ty; i < 32; i += 8)
        O[(long)(n0 + i) * ldo + k0 + tx] = (unsigned short)f2bf(t[tx][i]);
}

// corr f32 [E][882] -> bf16 [E][896] (padded); also zero-fills zrow (4KB).
__global__ __launch_bounds__(256)
void corrconv(const float* __restrict__ corr, unsigned int* __restrict__ corrb,
              unsigned int* __restrict__ zr)
{
    if (blockIdx.x == 0 && threadIdx.x < 1024) zr[threadIdx.x] = 0u;
    const long idx = (long)blockIdx.x * 256 + threadIdx.x;
    if (idx >= (long)ETOK * (CORR_PAD / 2)) return;
    const long e = idx / (CORR_PAD / 2);
    const int  p = (int)(idx % (CORR_PAD / 2));
    const int  k = p * 2;
    unsigned v = 0u;
    if (k + 1 < CORR_DIMV) {
        const float2 f = *(const float2*)(corr + e * CORR_DIMV + k);
        v = f2bf(f.x) | (f2bf(f.y) << 16);
    }
    corrb[idx] = v;
}

// concat biases: bqkv[1152] = bq|bk|bv ; bgf[768] = bg|bf
__global__ __launch_bounds__(256)
void biascat(const float* __restrict__ bq, const float* __restrict__ bk,
             const float* __restrict__ bv, const float* __restrict__ bg,
             const float* __restrict__ bf_, float* __restrict__ bqkv,
             float* __restrict__ bgf)
{
    const int t = blockIdx.x * 256 + threadIdx.x;
    if (t < 384)       { bqkv[t] = bq[t];       bgf[t] = bg[t]; }
    else if (t < 768)  { bqkv[t] = bk[t - 384]; bgf[t] = bf_[t - 384]; }
    else if (t < 1152) { bqkv[t] = bv[t - 768]; }
}

// ---------------------------------------------------------------------------
// LayerNorm (one wave per row), bf16 out.
// MODE 0: x = bf2f(sb[row]);  MODE 1: x = s0 + s1 + bf2f(sb);
// MODE 2: x = bf2f(sb[gather]) + seg[gather/24]
// ---------------------------------------------------------------------------
template<int MODE, bool RELUB>
__global__ __launch_bounds__(256)
void ln_kernel(unsigned short* __restrict__ dstb, int ldb,
               const float* __restrict__ s0, const float* __restrict__ s1,
               const unsigned short* __restrict__ sb,
               const float* __restrict__ seg, const int* __restrict__ gather,
               const float* __restrict__ g, const float* __restrict__ b)
{
    const int wave = threadIdx.x >> 6;
    const int lane = threadIdx.x & 63;
    const long row = (long)blockIdx.x * 4 + wave;
    const long srow = (MODE == 2) ? (long)gather[row] : row;

    float x[6];
    float sum = 0.f;
    #pragma unroll
    for (int i = 0; i < 6; ++i) {
        int c = lane + i * 64;
        float v;
        if (MODE == 0) v = bf2f(sb[srow * DIMV + c]);
        if (MODE == 1) v = s0[srow * DIMV + c] + s1[srow * DIMV + c] + bf2f(sb[srow * DIMV + c]);
        if (MODE == 2) v = bf2f(sb[srow * DIMV + c]) + seg[(srow / NFRAMESV) * DIMV + c];
        x[i] = v; sum += v;
    }
    #pragma unroll
    for (int o = 32; o > 0; o >>= 1) sum += __shfl_xor(sum, o);
    float mu = sum * (1.f / DIMV);
    float vs = 0.f;
    #pragma unroll
    for (int i = 0; i < 6; ++i) { float d = x[i] - mu; vs += d * d; }
    #pragma unroll
    for (int o = 32; o > 0; o >>= 1) vs += __shfl_xor(vs, o);
    float rstd = rsqrtf(vs * (1.f / DIMV) + 1e-3f);
    #pragma unroll
    for (int i = 0; i < 6; ++i) {
        int c = lane + i * 64;
        float y = (x[i] - mu) * rstd * g[c] + b[c];
        dstb[row * (long)ldb + c] = (unsigned short)f2bf(RELUB ? fmaxf(y, 0.f) : y);
    }
}

// ---------------------------------------------------------------------------
// Segment softmax-aggregation; g/f interleaved in one [E][768] bf16 buffer.
// ---------------------------------------------------------------------------
__global__ __launch_bounds__(384)
void softagg_kernel(const unsigned short* __restrict__ gf,
                    unsigned short* __restrict__ yb)
{
    const int p = blockIdx.x;
    const int col = threadIdx.x;
    const long base = (long)p * NFRAMESV * 768 + col;
    float gv[NFRAMESV];
    float gmax = -INFINITY;
    #pragma unroll
    for (int r = 0; r < NFRAMESV; ++r) {
        gv[r] = bf2f(gf[base + (long)r * 768]);
        gmax = fmaxf(gmax, gv[r]);
    }
    float den = 0.f;
    #pragma unroll
    for (int r = 0; r < NFRAMESV; ++r) { gv[r] = expf(gv[r] - gmax); den += gv[r]; }
    float acc = 0.f;
    #pragma unroll
    for (int r = 0; r < NFRAMESV; ++r) acc += bf2f(gf[base + 384 + (long)r * 768]) * gv[r];
    yb[(long)p * DIMV + col] = (unsigned short)f2bf(acc / den);
}

// ---------------------------------------------------------------------------
// RoPE + elu+1 on q and k in place, bf16, row stride ld.
// ---------------------------------------------------------------------------
__global__ __launch_bounds__(256)
void rope_kernel(unsigned short* __restrict__ q, unsigned short* __restrict__ k,
                 int ld, const float* __restrict__ pos, const int* __restrict__ flat)
{
    const long idx = (long)blockIdx.x * 256 + threadIdx.x;
    const long e = idx / 48;
    const int rem = (int)(idx % 48);
    const int h = rem / 6, d4 = (rem % 6) * 4;
    const int tok = flat[e];
    const float* cp = pos + (long)tok * HDV;
    const float* sp = pos + (long)ETOK * HDV + (long)tok * HDV;
    const float4 c1 = *(const float4*)(cp + d4);
    const float4 c2 = *(const float4*)(cp + d4 + 24);
    const float4 s1 = *(const float4*)(sp + d4);
    const float4 s2 = *(const float4*)(sp + d4 + 24);
    const long o1 = e * ld + h * HDV + d4;
    const long o2 = o1 + 24;

    float c1a[4] = {c1.x, c1.y, c1.z, c1.w};
    float c2a[4] = {c2.x, c2.y, c2.z, c2.w};
    float s1a[4] = {s1.x, s1.y, s1.z, s1.w};
    float s2a[4] = {s2.x, s2.y, s2.z, s2.w};

    u16x4 q1 = *(const u16x4*)&q[o1];
    u16x4 q2 = *(const u16x4*)&q[o2];
    u16x4 k1 = *(const u16x4*)&k[o1];
    u16x4 k2 = *(const u16x4*)&k[o2];
    u16x4 q1o, q2o, k1o, k2o;
    #pragma unroll
    for (int i = 0; i < 4; ++i) {
        const float qa = bf2f(q1[i]), qb = bf2f(q2[i]);
        float r1 = qa * c1a[i] - qb * s1a[i];
        float r2 = qb * c2a[i] + qa * s2a[i];
        r1 = (r1 > 0.f) ? r1 + 1.f : expf(r1);
        r2 = (r2 > 0.f) ? r2 + 1.f : expf(r2);
        q1o[i] = (unsigned short)f2bf(r1);
        q2o[i] = (unsigned short)f2bf(r2);
        const float ka = bf2f(k1[i]), kb = bf2f(k2[i]);
        float t1 = ka * c1a[i] - kb * s1a[i];
        float t2 = kb * c2a[i] + ka * s2a[i];
        t1 = (t1 > 0.f) ? t1 + 1.f : expf(t1);
        t2 = (t2 > 0.f) ? t2 + 1.f : expf(t2);
        k1o[i] = (unsigned short)f2bf(t1);
        k2o[i] = (unsigned short)f2bf(t2);
    }
    *(u16x4*)&q[o1] = q1o;
    *(u16x4*)&q[o2] = q2o;
    *(u16x4*)&k[o1] = k1o;
    *(u16x4*)&k[o2] = k2o;
}

// ---------------------------------------------------------------------------
// Gated linear attention core — MFMA, one WAVE per (group n, head h), bf16 io.
// ---------------------------------------------------------------------------
__global__ __launch_bounds__(256)
void attn_kernel(const unsigned short* __restrict__ qb,
                 const unsigned short* __restrict__ kb,
                 const unsigned short* __restrict__ vb, int ld,
                 unsigned short* __restrict__ ob, int ldo)
{
    __shared__ unsigned short KVt[4][48][64];
    __shared__ float KsumS[4][48];
    __shared__ float ZlS[4][96];

    const int tid  = threadIdx.x;
    const int wid  = tid >> 6;
    const int lane = tid & 63;
    const int task = blockIdx.x * 4 + wid;
    const int n = task >> 3, h = task & 7;

    const long base  = ((long)n * MTOK) * ld + h * HDV;
    const long baseo = ((long)n * MTOK) * ldo + h * HDV;

    const int c16   = lane & 15;
    const int kq    = lane >> 4;
    const int khalf = kq * 8;

    if (lane < 48) {
        const int s = (lane & 7) << 3;
        const uint4 z = make_uint4(0u, 0u, 0u, 0u);
        *(uint4*)&KVt[wid][lane][48 ^ s] = z;
        *(uint4*)&KVt[wid][lane][56 ^ s] = z;
    }

    f32x4 kv[3][3] = {};
    float ksum_p[3] = {0.f, 0.f, 0.f};

    for (int ks = 0; ks < 3; ++ks) {
        const int l0 = ks * 32 + khalf;
        s16x8 afr[3], bfr[3];
        #pragma unroll
        for (int mf = 0; mf < 3; ++mf) {
            const int d = mf * 16 + c16;
            union { unsigned short us[8]; s16x8 v; } pk;
            float s = 0.f;
            #pragma unroll
            for (int j = 0; j < 8; ++j) {
                const unsigned short kw = kb[base + (long)(l0 + j) * ld + d];
                s += bf2f(kw);
                pk.us[j] = kw;
            }
            ksum_p[mf] += s;
            afr[mf] = pk.v;
        }
        #pragma unroll
        for (int nf = 0; nf < 3; ++nf) {
            const int dv = nf * 16 + c16;
            union { unsigned short us[8]; s16x8 v; } pk;
            #pragma unroll
            for (int j = 0; j < 8; ++j)
                pk.us[j] = vb[base + (long)(l0 + j) * ld + dv];
            bfr[nf] = pk.v;
        }
        #pragma unroll
        for (int mf = 0; mf < 3; ++mf)
            #pragma unroll
            for (int nf = 0; nf < 3; ++nf)
                kv[mf][nf] = __builtin_amdgcn_mfma_f32_16x16x32_bf16(afr[mf], bfr[nf], kv[mf][nf], 0, 0, 0);
    }

    #pragma unroll
    for (int mf = 0; mf < 3; ++mf) {
        float s = ksum_p[mf];
        s += __shfl_xor(s, 16);
        s += __shfl_xor(s, 32);
        if (kq == 0) KsumS[wid][mf * 16 + c16] = s;
    }

    #pragma unroll
    for (int mf = 0; mf < 3; ++mf) {
        #pragma unroll
        for (int nf = 0; nf < 3; ++nf) {
            const int dv = nf * 16 + c16;
            const int d0 = (mf * 16 + kq * 4) ^ ((dv & 7) << 3);
            uint2 w;
            w.x = f2bf(kv[mf][nf][0]) | (f2bf(kv[mf][nf][1]) << 16);
            w.y = f2bf(kv[mf][nf][2]) | (f2bf(kv[mf][nf][3]) << 16);
            *(uint2*)&KVt[wid][dv][d0] = w;
        }
    }

    s16x8 qf[6][2];
    const s16x8 zfrag = {0, 0, 0, 0, 0, 0, 0, 0};
    #pragma unroll
    for (int mf = 0; mf < 6; ++mf) {
        const int l = mf * 16 + c16;
        float dsum = 0.f;
        #pragma unroll
        for (int ks = 0; ks < 2; ++ks) {
            if (ks == 0 || kq < 2) {
                const int d = ks * 32 + khalf;
                union { unsigned short us[8]; s16x8 v; } pk;
                pk.v = *(const s16x8*)&qb[base + (long)l * ld + d];
                #pragma unroll
                for (int j = 0; j < 8; ++j)
                    dsum += bf2f(pk.us[j]) * KsumS[wid][d + j];
                qf[mf][ks] = pk.v;
            } else {
                qf[mf][ks] = zfrag;
            }
        }
        dsum += __shfl_xor(dsum, 16);
        dsum += __shfl_xor(dsum, 32);
        if (kq == 0) ZlS[wid][l] = 1.f / (dsum + 1e-6f);
    }

    #pragma unroll
    for (int nf = 0; nf < 3; ++nf) {
        const int dv = nf * 16 + c16;
        const int sw = (dv & 7) << 3;
        const s16x8 b0 = *(const s16x8*)&KVt[wid][dv][khalf ^ sw];
        const s16x8 b1 = *(const s16x8*)&KVt[wid][dv][(32 + khalf) ^ sw];
        #pragma unroll
        for (int mf = 0; mf < 6; ++mf) {
            f32x4 a = {};
            a = __builtin_amdgcn_mfma_f32_16x16x32_bf16(qf[mf][0], b0, a, 0, 0, 0);
            a = __builtin_amdgcn_mfma_f32_16x16x32_bf16(qf[mf][1], b1, a, 0, 0, 0);
            const int lb = mf * 16 + kq * 4;
            const long rbase = baseo + (long)lb * ldo + dv;
            #pragma unroll
            for (int rr = 0; rr < 4; ++rr) {
                const float z = ZlS[wid][lb + rr];
                ob[rbase + (long)rr * ldo] = (unsigned short)f2bf(a[rr] * z);
            }
        }
    }
}

// finish heads: d = partial + bd ; w = sigmoid(partial + bw)
__global__ __launch_bounds__(256)
void head_fin(const float* __restrict__ hdw,
              const float* __restrict__ bd, const float* __restrict__ bw,
              float* __restrict__ dout, float* __restrict__ wout)
{
    const long r = (long)blockIdx.x * 256 + threadIdx.x;
    dout[r * 2 + 0] = hdw[r * 4 + 0] + bd[0];
    dout[r * 2 + 1] = hdw[r * 4 + 1] + bd[1];
    wout[r * 2 + 0] = 1.f / (1.f + expf(-(hdw[r * 4 + 2] + bw[0])));
    wout[r * 2 + 1] = 1.f / (1.f + expf(-(hdw[r * 4 + 3] + bw[1])));
}

extern "C" void kernel_launch(void* const* d_in, const int* in_sizes, int n_in,
                              void* d_out, int out_size, void* d_ws, size_t ws_size,
                              hipStream_t stream)
{
    const float* net_in = (const float*)d_in[0];
    const float* inp    = (const float*)d_in[1];
    const float* corr   = (const float*)d_in[2];
    const float* posenc = (const float*)d_in[4];
    const int*   ix     = (const int*)d_in[8];
    const int*   jx     = (const int*)d_in[9];
    const int*   flat   = (const int*)d_in[10];

    const float* Wc1 = (const float*)d_in[11]; const float* bc1 = (const float*)d_in[12];
    const float* Wc2 = (const float*)d_in[13]; const float* bc2 = (const float*)d_in[14];
    const float* g_lnc = (const float*)d_in[15]; const float* b_lnc = (const float*)d_in[16];
    const float* Wc3 = (const float*)d_in[17]; const float* bc3 = (const float*)d_in[18];
    const float* g_norm = (const float*)d_in[19]; const float* b_norm = (const float*)d_in[20];
    const float* W1a = (const float*)d_in[21]; const float* b1a = (const float*)d_in[22];
    const float* W1b = (const float*)d_in[23]; const float* b1b = (const float*)d_in[24];
    const float* W2a = (const float*)d_in[25]; const float* b2a = (const float*)d_in[26];
    const float* W2b = (const float*)d_in[27]; const float* b2b = (const float*)d_in[28];
    const float* Wf = (const float*)d_in[29]; const float* bff = (const float*)d_in[30];
    const float* Wg = (const float*)d_in[31]; const float* bg = (const float*)d_in[32];
    const float* Wh = (const float*)d_in[33]; const float* bh = (const float*)d_in[34];
    const float* g_norm2 = (const float*)d_in[35]; const float* b_norm2 = (const float*)d_in[36];
    const float* Wq = (const float*)d_in[37]; const float* bq = (const float*)d_in[38];
    const float* Wk = (const float*)d_in[39]; const float* bk = (const float*)d_in[40];
    const float* Wv = (const float*)d_in[41]; const float* bv = (const float*)d_in[42];
    const float* Wm = (const float*)d_in[43]; const float* bm = (const float*)d_in[44];
    const float* Wgt = (const float*)d_in[45]; const float* bgt = (const float*)d_in[46];
    const float* Wd = (const float*)d_in[47]; const float* bd = (const float*)d_in[48];
    const float* Ww = (const float*)d_in[49]; const float* bw = (const float*)d_in[50];

    // ---- workspace layout ----
    const size_t EB  = (size_t)ETOK * DIMV;
    const size_t WSLOT = (size_t)DIMV * DIMV;
    char* p = (char*)d_ws;
    float* Y2f = (float*)p;           p += (size_t)NPATCHV * DIMV * 4;
    unsigned short* WT = (unsigned short*)p;
    p += (13 * WSLOT + (size_t)DIMV * CORR_PAD + (size_t)DIMV * 768) * 2;
    unsigned short* ZR  = (unsigned short*)p; p += 4096;
    float* bqkv = (float*)p;          p += 1152 * 4;
    float* bgf  = (float*)p;          p += 768 * 4;
    unsigned short* Cb0 = (unsigned short*)p; p += EB * 2;
    unsigned short* Bb  = (unsigned short*)p; p += EB * 2;
    unsigned short* Xb1 = (unsigned short*)p; p += EB * 2;
    unsigned short* Xb2 = (unsigned short*)p; p += EB * 2;
    unsigned short* Xgf = (unsigned short*)p; p += (size_t)ETOK * 768 * 2;
    unsigned short* TM  = (unsigned short*)p; p += (size_t)ETOK * 768 * 2;
    unsigned short* Yb  = (unsigned short*)p; p += (size_t)NPATCHV * DIMV * 2;
    unsigned short* QKV = (unsigned short*)p; p += (size_t)ETOK * 1152 * 2;
    float* hdw = (float*)p;           p += (size_t)ETOK * 4 * 4;
    unsigned short* corrb = QKV;   // overlay: corrb (99MB) over QKV (127MB)

    unsigned short* Wc2t = WT + 0 * WSLOT;
    unsigned short* Wc3t = WT + 1 * WSLOT;
    unsigned short* W1at = WT + 2 * WSLOT;
    unsigned short* W1bt = WT + 3 * WSLOT;
    unsigned short* W2at = WT + 4 * WSLOT;
    unsigned short* W2bt = WT + 5 * WSLOT;
    unsigned short* WgfT = WT + 6 * WSLOT;   // [768][384]: Wg | Wf
    unsigned short* Wht  = WT + 8 * WSLOT;
    unsigned short* Wqkv = WT + 9 * WSLOT;   // [1152][384]: Wq | Wk | Wv
    unsigned short* Wmt  = WT + 12 * WSLOT;
    unsigned short* Wc1t = WT + 13 * WSLOT;                 // [384][896]
    unsigned short* Wgtt = Wc1t + (size_t)DIMV * CORR_PAD;  // [384][768]

    float* out_net = (float*)d_out;
    float* out_d = out_net + EB;
    float* out_w = out_d + (size_t)ETOK * 2;

    const dim3 gB(DIMV / 128, ETOK / 128);      // (3, 432)
    const dim3 gGF(768 / 128, ETOK / 128);      // (6, 432)
    const dim3 gQKV(1152 / 128, ETOK / 128);    // (9, 432)
    const dim3 gY(DIMV / 128, NPATCHV / 128);   // (3, 18)
    const int lnBlocks = ETOK / 4;

    // ---- pre-passes ----
    {
        const long tot = (long)ETOK * (CORR_PAD / 2);
        corrconv<<<(int)((tot + 255) / 256), 256, 0, stream>>>(corr, (unsigned int*)corrb, (unsigned int*)ZR);
    }
    {
        WPtrs13 w;
        w.p[0] = Wc2; w.p[1] = Wc3; w.p[2] = W1a; w.p[3] = W1b; w.p[4] = W2a;
        w.p[5] = W2b; w.p[6] = Wg;  w.p[7] = Wf;  w.p[8] = Wh;  w.p[9] = Wq;
        w.p[10] = Wk; w.p[11] = Wv; w.p[12] = Wm;
        wtrans13<<<dim3(12, 12, 13), dim3(32, 8), 0, stream>>>(w, WT);
        wtransb<<<dim3(28, 12), dim3(32, 8), 0, stream>>>(Wc1, Wc1t, CORR_DIMV, CORR_PAD);
        wtransb<<<dim3(24, 12), dim3(32, 8), 0, stream>>>(Wgt, Wgtt, 768, 768);
        biascat<<<5, 256, 0, stream>>>(bq, bk, bv, bg, bff, bqkv, bgf);
        hipMemsetAsync(hdw, 0, (size_t)ETOK * 4 * sizeof(float), stream);
    }

    // corr encoder
    gemm_bb<1, false><<<gB, 256, 0, stream>>>(corrb, CORR_PAD, Wc1t, bc1, nullptr, Cb0, DIMV, 0, nullptr, ZR, CORR_PAD, nullptr, nullptr, nullptr);
    gemm_bb<5, false><<<gB, 256, 0, stream>>>(Cb0, DIMV, Wc2t, bc2, nullptr, Xb1, DIMV, 0, nullptr, ZR, DIMV, nullptr, nullptr, nullptr);
    ln_kernel<0, true><<<lnBlocks, 256, 0, stream>>>(Cb0, DIMV, nullptr, nullptr, Xb1, nullptr, nullptr, g_lnc, b_lnc);
    gemm_bb<5, false><<<gB, 256, 0, stream>>>(Cb0, DIMV, Wc3t, bc3, nullptr, Xb2, DIMV, 0, nullptr, ZR, DIMV, nullptr, nullptr, nullptr);

    // net = LN(net + inp + c) -> Bb (bf16)
    ln_kernel<1, false><<<lnBlocks, 256, 0, stream>>>(Bb, DIMV, net_in, inp, Xb2, nullptr, nullptr, g_norm, b_norm);

    // net += mlp2(mask_ix * net[ix])
    gemm_bb<1, true><<<gB, 256, 0, stream>>>(Bb, DIMV, W1at, b1a, nullptr, Cb0, DIMV, 0, ix, ZR, DIMV, nullptr, nullptr, nullptr);
    gemm_bb<6, false><<<gB, 256, 0, stream>>>(Cb0, DIMV, W1bt, b1b, nullptr, Bb, DIMV, 0, nullptr, ZR, DIMV, nullptr, nullptr, nullptr);

    // net += mlp2(mask_jx * net[jx])
    gemm_bb<1, true><<<gB, 256, 0, stream>>>(Bb, DIMV, W2at, b2a, nullptr, Cb0, DIMV, 0, jx, ZR, DIMV, nullptr, nullptr, nullptr);
    gemm_bb<6, false><<<gB, 256, 0, stream>>>(Cb0, DIMV, W2bt, b2b, nullptr, Bb, DIMV, 0, nullptr, ZR, DIMV, nullptr, nullptr, nullptr);

    // soft aggregation: g|f in one N=768 GEMM
    gemm_bb<5, false><<<gGF, 256, 0, stream>>>(Bb, DIMV, WgfT, bgf, nullptr, Xgf, 768, 0, nullptr, ZR, DIMV, nullptr, nullptr, nullptr);
    softagg_kernel<<<NPATCHV, 384, 0, stream>>>(Xgf, Yb);
    gemm_bb<0, false><<<gY, 256, 0, stream>>>(Yb, DIMV, Wht, bh, Y2f, nullptr, DIMV, 0, nullptr, ZR, DIMV, nullptr, nullptr, nullptr);

    // tokens = LN(net[flat] + Y2[flat/24]) -> TM[:, 0:384] bf16
    ln_kernel<2, false><<<lnBlocks, 256, 0, stream>>>(TM, 768, nullptr, nullptr, Bb, Y2f, flat, g_norm2, b_norm2);

    // q|k|v in one N=1152 GEMM -> QKV [E][1152]
    gemm_bb<5, false><<<gQKV, 256, 0, stream>>>(TM, 768, Wqkv, bqkv, nullptr, QKV, 1152, 0, nullptr, ZR, DIMV, nullptr, nullptr, nullptr);

    // RoPE + elu+1 on q,k (bf16 in place)
    rope_kernel<<<(int)((long)ETOK * 48 / 256), 256, 0, stream>>>(QKV, QKV + 384, 1152, posenc, flat);

    // linear attention -> Cb0 (bf16)
    attn_kernel<<<NGRP * NHEADV / 4, 256, 0, stream>>>(QKV, QKV + 384, QKV + 768, 1152, Cb0, DIMV);

    // msg = out @ Wm + bm -> TM[:, 384:768] bf16
    gemm_bb<5, false><<<gB, 256, 0, stream>>>(Cb0, DIMV, Wmt, bm, nullptr, TM, 768, 384, nullptr, ZR, DIMV, nullptr, nullptr, nullptr);

    // gate+combine + fused head partials:
    // out_net[flat[e]] = tok + sigmoid(TM @ Wgt + bgt) * msg ; hdw += head partials
    gemm_bb<7, false><<<gB, 256, 0, stream>>>(TM, 768, Wgtt, bgt, out_net, TM, 768, 384, flat, ZR, 768, Wd, Ww, hdw);

    // finish heads
    head_fin<<<ETOK / 256, 256, 0, stream>>>(hdw, bd, bw, out_d, out_w);
}

// Round 13
// 881.581 us; speedup vs baseline: 1.1149x; 1.0438x over previous
//
#include <hip/hip_runtime.h>
#include <math.h>

#define DIMV 384
#define NHEADV 8
#define HDV 48
#define CORR_DIMV 882
#define CORR_PAD 896
#define NFRAMESV 24
#define PPIV 96
#define NPATCHV (NFRAMESV * PPIV)        // 2304
#define ETOK (NPATCHV * NFRAMESV)        // 55296
#define MTOK 96
#define NGRP (ETOK / MTOK)               // 576

using f32x4 = __attribute__((ext_vector_type(4))) float;
using s16x8 = __attribute__((ext_vector_type(8))) short;
using u16x4 = __attribute__((ext_vector_type(4))) unsigned short;

__device__ __forceinline__ unsigned int f2bf(float x) {
    union { float f; unsigned int u; } c; c.f = x;
    unsigned int u = c.u;
    u += 0x7fffu + ((u >> 16) & 1u);   // round-to-nearest-even
    return u >> 16;
}
__device__ __forceinline__ float bf2f(unsigned short x) {
    union { unsigned int u; float f; } c; c.u = ((unsigned int)x) << 16;
    return c.f;
}

__device__ __forceinline__ void gload_lds16(const void* g, void* l) {
    __builtin_amdgcn_global_load_lds(
        (const __attribute__((address_space(1))) unsigned int*)g,
        (__attribute__((address_space(3))) unsigned int*)l, 16, 0, 0);
}

// Bijective XCD-chunked block swizzle (m204).
__device__ __forceinline__ void xcd_tile(int& colblk, int& rowblk) {
    const int nwg  = gridDim.x * gridDim.y;
    const int flat = blockIdx.y * gridDim.x + blockIdx.x;
    const int xcd  = flat & 7;
    const int base = flat >> 3;
    const int q = nwg >> 3, r = nwg & 7;
    const int nf = (xcd < r ? xcd * (q + 1) : r * (q + 1) + (xcd - r) * q) + base;
    colblk = nf % gridDim.x;
    rowblk = nf / gridDim.x;
}

// ---------------------------------------------------------------------------
// Single GEMM: round-7 measured-best K-loop (2-buf, vmcnt(4), 2 barriers/tile).
// Session post-mortems baked in:
//  - fused2 (per-wave W streaming): latency-bound, 275µs — dead end.
//  - gemm_f32a (reg-staged f32 A): uncoalesced row loads, 230µs — dead end.
//  - 3-buffer ring / 1 barrier: neutral (898 vs 883) — keep 2-buf.
//  - head fusion into EPI7: +37µs (epilogue serial work > 12µs head pass).
// EPI: 0 = f32 store, 1 = bf16 relu store, 5 = bf16 store,
//      6 = bf16 in-place accumulate, 7 = gate-combine.
// GATHER: A row r is A[gidx[r]]; gidx[r] < 0 -> reads zrow (zeroed region).
// ---------------------------------------------------------------------------
template<int EPI, bool GATHER>
__global__ __launch_bounds__(256)
void gemm_bb(const unsigned short* __restrict__ A, int lda,
             const unsigned short* __restrict__ Wt,
             const float* __restrict__ bias,
             float* __restrict__ C,
             unsigned short* __restrict__ Cb, int ldcb, int cbofs,
             const int* __restrict__ gidx,
             const unsigned short* __restrict__ zrow, int K)
{
    int colblk, rowblk;
    xcd_tile(colblk, rowblk);
    const int row0 = rowblk * 128;
    const int col0 = colblk * 128;

    __shared__ __align__(16) unsigned short As[2 * 128 * 32];
    __shared__ __align__(16) unsigned short Bs[2 * 128 * 32];

    const int tid  = threadIdx.x;
    const int lane = tid & 63;
    const int wid  = tid >> 6;
    const int wm   = wid >> 1;
    const int wn   = wid & 1;

    const int rl = lane >> 2;
    const int cp = lane & 3;

    const unsigned short* asrc[2];
    const unsigned short* bsrc[2];
    #pragma unroll
    for (int s = 0; s < 2; ++s) {
        const int r = wid * 32 + s * 16 + rl;
        const int c = cp ^ ((r >> 1) & 3);
        long arow = row0 + r;
        if (GATHER) arow = gidx[row0 + r];
        asrc[s] = (GATHER && arow < 0) ? (zrow + c * 8)
                                       : (A + arow * (long)lda + c * 8);
        bsrc[s] = Wt + (long)(col0 + r) * K + c * 8;
    }

    f32x4 acc[4][4] = {};
    const int ntiles = K >> 5;
    const int rsel = lane & 15;
    const int kq   = lane >> 4;

    auto stage = [&](int b, int ko) {
        unsigned short* a0 = &As[b * 4096 + wid * 1024];
        unsigned short* b0 = &Bs[b * 4096 + wid * 1024];
        gload_lds16(asrc[0] + ko, a0);
        gload_lds16(asrc[1] + ko, a0 + 512);
        gload_lds16(bsrc[0] + ko, b0);
        gload_lds16(bsrc[1] + ko, b0 + 512);
    };
    auto body = [&](int b) {
        const unsigned short* Ab = &As[b * 4096];
        const unsigned short* Bf = &Bs[b * 4096];
        s16x8 a[4], w[4];
        #pragma unroll
        for (int i = 0; i < 4; ++i) {
            const int R = wm * 64 + i * 16 + rsel;
            a[i] = *(const s16x8*)&Ab[R * 32 + ((kq ^ ((R >> 1) & 3)) << 3)];
        }
        #pragma unroll
        for (int j = 0; j < 4; ++j) {
            const int R = wn * 64 + j * 16 + rsel;
            w[j] = *(const s16x8*)&Bf[R * 32 + ((kq ^ ((R >> 1) & 3)) << 3)];
        }
        #pragma unroll
        for (int i = 0; i < 4; ++i)
            #pragma unroll
            for (int j = 0; j < 4; ++j)
                acc[i][j] = __builtin_amdgcn_mfma_f32_16x16x32_bf16(a[i], w[j], acc[i][j], 0, 0, 0);
    };

    stage(0, 0);
    int cur = 0;
    for (int t = 0; t + 1 < ntiles; ++t) {
        stage(cur ^ 1, (t + 1) << 5);
        asm volatile("s_waitcnt vmcnt(4)\n\ts_barrier" ::: "memory");
        body(cur);
        asm volatile("s_barrier" ::: "memory");
        cur ^= 1;
    }
    asm volatile("s_waitcnt vmcnt(0)\n\ts_barrier" ::: "memory");
    body(cur);

    const int ccol = lane & 15;
    const int rgrp = lane >> 4;
    #pragma unroll
    for (int i = 0; i < 4; ++i) {
        const long rbase = row0 + wm * 64 + i * 16 + rgrp * 4;
        #pragma unroll
        for (int j = 0; j < 4; ++j) {
            const int col = col0 + wn * 64 + j * 16 + ccol;
            const float bsv = bias ? bias[col] : 0.f;
            #pragma unroll
            for (int rr = 0; rr < 4; ++rr) {
                const long row = rbase + rr;
                float v = acc[i][j][rr] + bsv;
                if (EPI == 0) C[row * (long)DIMV + col] = v;
                if (EPI == 1) Cb[row * (long)ldcb + cbofs + col] = (unsigned short)f2bf(fmaxf(v, 0.f));
                if (EPI == 5) Cb[row * (long)ldcb + cbofs + col] = (unsigned short)f2bf(v);
                if (EPI == 6) { const long off = row * (long)ldcb + col;
                                Cb[off] = (unsigned short)f2bf(bf2f(Cb[off]) + v); }
                if (EPI == 7) {
                    const float gate = 1.f / (1.f + expf(-v));
                    const float tok  = bf2f(Cb[row * (long)ldcb + col]);
                    const float msg  = bf2f(Cb[row * (long)ldcb + cbofs + col]);
                    C[(long)gidx[row] * DIMV + col] = tok + gate * msg;
                }
            }
        }
    }
}

// ---------------------------------------------------------------------------
// Weight transpose+convert. Slot order matters: 6=Wg,7=Wf (merged N=768),
// 9=Wq,10=Wk,11=Wv (merged N=1152).
// ---------------------------------------------------------------------------
struct WPtrs13 { const float* p[13]; };

__global__ __launch_bounds__(256)
void wtrans13(WPtrs13 w, unsigned short* __restrict__ out)
{
    __shared__ float t[32][33];
    const float* W = w.p[blockIdx.z];
    unsigned short* O = out + (size_t)blockIdx.z * DIMV * DIMV;
    const int k0 = blockIdx.x * 32, n0 = blockIdx.y * 32;
    const int tx = threadIdx.x, ty = threadIdx.y;
    #pragma unroll
    for (int i = ty; i < 32; i += 8)
        t[i][tx] = W[(long)(k0 + i) * DIMV + n0 + tx];
    __syncthreads();
    #pragma unroll
    for (int i = ty; i < 32; i += 8)
        O[(long)(n0 + i) * DIMV + k0 + tx] = (unsigned short)f2bf(t[tx][i]);
}

// generic: W [krows][384] f32 -> O [384][ldo] bf16 (zero-padded k >= krows)
__global__ __launch_bounds__(256)
void wtransb(const float* __restrict__ W, unsigned short* __restrict__ O,
             int krows, int ldo)
{
    __shared__ float t[32][33];
    const int k0 = blockIdx.x * 32, n0 = blockIdx.y * 32;
    const int tx = threadIdx.x, ty = threadIdx.y;
    #pragma unroll
    for (int i = ty; i < 32; i += 8)
        t[i][tx] = (k0 + i < krows) ? W[(long)(k0 + i) * DIMV + n0 + tx] : 0.f;
    __syncthreads();
    #pragma unroll
    for (int i = ty; i < 32; i += 8)
        O[(long)(n0 + i) * ldo + k0 + tx] = (unsigned short)f2bf(t[tx][i]);
}

// corr f32 [E][882] -> bf16 [E][896] (padded); also zero-fills zrow (2KB).
__global__ __launch_bounds__(256)
void corrconv(const float* __restrict__ corr, unsigned int* __restrict__ corrb,
              unsigned int* __restrict__ zr)
{
    if (blockIdx.x == 0 && threadIdx.x < 512) zr[threadIdx.x] = 0u;
    const long idx = (long)blockIdx.x * 256 + threadIdx.x;
    if (idx >= (long)ETOK * (CORR_PAD / 2)) return;
    const long e = idx / (CORR_PAD / 2);
    const int  p = (int)(idx % (CORR_PAD / 2));
    const int  k = p * 2;
    unsigned v = 0u;
    if (k + 1 < CORR_DIMV) {
        const float2 f = *(const float2*)(corr + e * CORR_DIMV + k);
        v = f2bf(f.x) | (f2bf(f.y) << 16);
    }
    corrb[idx] = v;
}

// concat biases: bqkv[1152] = bq|bk|bv ; bgf[768] = bg|bf
__global__ __launch_bounds__(256)
void biascat(const float* __restrict__ bq, const float* __restrict__ bk,
             const float* __restrict__ bv, const float* __restrict__ bg,
             const float* __restrict__ bf_, float* __restrict__ bqkv,
             float* __restrict__ bgf)
{
    const int t = blockIdx.x * 256 + threadIdx.x;
    if (t < 384)       { bqkv[t] = bq[t];       bgf[t] = bg[t]; }
    else if (t < 768)  { bqkv[t] = bk[t - 384]; bgf[t] = bf_[t - 384]; }
    else if (t < 1152) { bqkv[t] = bv[t - 768]; }
}

// ---------------------------------------------------------------------------
// LayerNorm (one wave per row), bf16 out.
// MODE 0: x = bf2f(sb[row]);  MODE 1: x = s0 + s1 + bf2f(sb);
// MODE 2: x = bf2f(sb[gather]) + seg[gather/24]
// ---------------------------------------------------------------------------
template<int MODE, bool RELUB>
__global__ __launch_bounds__(256)
void ln_kernel(unsigned short* __restrict__ dstb, int ldb,
               const float* __restrict__ s0, const float* __restrict__ s1,
               const unsigned short* __restrict__ sb,
               const float* __restrict__ seg, const int* __restrict__ gather,
               const float* __restrict__ g, const float* __restrict__ b)
{
    const int wave = threadIdx.x >> 6;
    const int lane = threadIdx.x & 63;
    const long row = (long)blockIdx.x * 4 + wave;
    const long srow = (MODE == 2) ? (long)gather[row] : row;

    float x[6];
    float sum = 0.f;
    #pragma unroll
    for (int i = 0; i < 6; ++i) {
        int c = lane + i * 64;
        float v;
        if (MODE == 0) v = bf2f(sb[srow * DIMV + c]);
        if (MODE == 1) v = s0[srow * DIMV + c] + s1[srow * DIMV + c] + bf2f(sb[srow * DIMV + c]);
        if (MODE == 2) v = bf2f(sb[srow * DIMV + c]) + seg[(srow / NFRAMESV) * DIMV + c];
        x[i] = v; sum += v;
    }
    #pragma unroll
    for (int o = 32; o > 0; o >>= 1) sum += __shfl_xor(sum, o);
    float mu = sum * (1.f / DIMV);
    float vs = 0.f;
    #pragma unroll
    for (int i = 0; i < 6; ++i) { float d = x[i] - mu; vs += d * d; }
    #pragma unroll
    for (int o = 32; o > 0; o >>= 1) vs += __shfl_xor(vs, o);
    float rstd = rsqrtf(vs * (1.f / DIMV) + 1e-3f);
    #pragma unroll
    for (int i = 0; i < 6; ++i) {
        int c = lane + i * 64;
        float y = (x[i] - mu) * rstd * g[c] + b[c];
        dstb[row * (long)ldb + c] = (unsigned short)f2bf(RELUB ? fmaxf(y, 0.f) : y);
    }
}

// ---------------------------------------------------------------------------
// Segment softmax-aggregation; g/f interleaved in one [E][768] bf16 buffer.
// ---------------------------------------------------------------------------
__global__ __launch_bounds__(384)
void softagg_kernel(const unsigned short* __restrict__ gf,
                    unsigned short* __restrict__ yb)
{
    const int p = blockIdx.x;
    const int col = threadIdx.x;
    const long base = (long)p * NFRAMESV * 768 + col;
    float gv[NFRAMESV];
    float gmax = -INFINITY;
    #pragma unroll
    for (int r = 0; r < NFRAMESV; ++r) {
        gv[r] = bf2f(gf[base + (long)r * 768]);
        gmax = fmaxf(gmax, gv[r]);
    }
    float den = 0.f;
    #pragma unroll
    for (int r = 0; r < NFRAMESV; ++r) { gv[r] = expf(gv[r] - gmax); den += gv[r]; }
    float acc = 0.f;
    #pragma unroll
    for (int r = 0; r < NFRAMESV; ++r) acc += bf2f(gf[base + 384 + (long)r * 768]) * gv[r];
    yb[(long)p * DIMV + col] = (unsigned short)f2bf(acc / den);
}

// ---------------------------------------------------------------------------
// RoPE + elu+1 on q and k in place, bf16, row stride ld.
// ---------------------------------------------------------------------------
__global__ __launch_bounds__(256)
void rope_kernel(unsigned short* __restrict__ q, unsigned short* __restrict__ k,
                 int ld, const float* __restrict__ pos, const int* __restrict__ flat)
{
    const long idx = (long)blockIdx.x * 256 + threadIdx.x;
    const long e = idx / 48;
    const int rem = (int)(idx % 48);
    const int h = rem / 6, d4 = (rem % 6) * 4;
    const int tok = flat[e];
    const float* cp = pos + (long)tok * HDV;
    const float* sp = pos + (long)ETOK * HDV + (long)tok * HDV;
    const float4 c1 = *(const float4*)(cp + d4);
    const float4 c2 = *(const float4*)(cp + d4 + 24);
    const float4 s1 = *(const float4*)(sp + d4);
    const float4 s2 = *(const float4*)(sp + d4 + 24);
    const long o1 = e * ld + h * HDV + d4;
    const long o2 = o1 + 24;

    float c1a[4] = {c1.x, c1.y, c1.z, c1.w};
    float c2a[4] = {c2.x, c2.y, c2.z, c2.w};
    float s1a[4] = {s1.x, s1.y, s1.z, s1.w};
    float s2a[4] = {s2.x, s2.y, s2.z, s2.w};

    u16x4 q1 = *(const u16x4*)&q[o1];
    u16x4 q2 = *(const u16x4*)&q[o2];
    u16x4 k1 = *(const u16x4*)&k[o1];
    u16x4 k2 = *(const u16x4*)&k[o2];
    u16x4 q1o, q2o, k1o, k2o;
    #pragma unroll
    for (int i = 0; i < 4; ++i) {
        const float qa = bf2f(q1[i]), qb = bf2f(q2[i]);
        float r1 = qa * c1a[i] - qb * s1a[i];
        float r2 = qb * c2a[i] + qa * s2a[i];
        r1 = (r1 > 0.f) ? r1 + 1.f : expf(r1);
        r2 = (r2 > 0.f) ? r2 + 1.f : expf(r2);
        q1o[i] = (unsigned short)f2bf(r1);
        q2o[i] = (unsigned short)f2bf(r2);
        const float ka = bf2f(k1[i]), kb = bf2f(k2[i]);
        float t1 = ka * c1a[i] - kb * s1a[i];
        float t2 = kb * c2a[i] + ka * s2a[i];
        t1 = (t1 > 0.f) ? t1 + 1.f : expf(t1);
        t2 = (t2 > 0.f) ? t2 + 1.f : expf(t2);
        k1o[i] = (unsigned short)f2bf(t1);
        k2o[i] = (unsigned short)f2bf(t2);
    }
    *(u16x4*)&q[o1] = q1o;
    *(u16x4*)&q[o2] = q2o;
    *(u16x4*)&k[o1] = k1o;
    *(u16x4*)&k[o2] = k2o;
}

// ---------------------------------------------------------------------------
// Gated linear attention core — MFMA, one WAVE per (group n, head h), bf16 io.
// ---------------------------------------------------------------------------
__global__ __launch_bounds__(256)
void attn_kernel(const unsigned short* __restrict__ qb,
                 const unsigned short* __restrict__ kb,
                 const unsigned short* __restrict__ vb, int ld,
                 unsigned short* __restrict__ ob, int ldo)
{
    __shared__ unsigned short KVt[4][48][64];
    __shared__ float KsumS[4][48];
    __shared__ float ZlS[4][96];

    const int tid  = threadIdx.x;
    const int wid  = tid >> 6;
    const int lane = tid & 63;
    const int task = blockIdx.x * 4 + wid;
    const int n = task >> 3, h = task & 7;

    const long base  = ((long)n * MTOK) * ld + h * HDV;
    const long baseo = ((long)n * MTOK) * ldo + h * HDV;

    const int c16   = lane & 15;
    const int kq    = lane >> 4;
    const int khalf = kq * 8;

    if (lane < 48) {
        const int s = (lane & 7) << 3;
        const uint4 z = make_uint4(0u, 0u, 0u, 0u);
        *(uint4*)&KVt[wid][lane][48 ^ s] = z;
        *(uint4*)&KVt[wid][lane][56 ^ s] = z;
    }

    f32x4 kv[3][3] = {};
    float ksum_p[3] = {0.f, 0.f, 0.f};

    for (int ks = 0; ks < 3; ++ks) {
        const int l0 = ks * 32 + khalf;
        s16x8 afr[3], bfr[3];
        #pragma unroll
        for (int mf = 0; mf < 3; ++mf) {
            const int d = mf * 16 + c16;
            union { unsigned short us[8]; s16x8 v; } pk;
            float s = 0.f;
            #pragma unroll
            for (int j = 0; j < 8; ++j) {
                const unsigned short kw = kb[base + (long)(l0 + j) * ld + d];
                s += bf2f(kw);
                pk.us[j] = kw;
            }
            ksum_p[mf] += s;
            afr[mf] = pk.v;
        }
        #pragma unroll
        for (int nf = 0; nf < 3; ++nf) {
            const int dv = nf * 16 + c16;
            union { unsigned short us[8]; s16x8 v; } pk;
            #pragma unroll
            for (int j = 0; j < 8; ++j)
                pk.us[j] = vb[base + (long)(l0 + j) * ld + dv];
            bfr[nf] = pk.v;
        }
        #pragma unroll
        for (int mf = 0; mf < 3; ++mf)
            #pragma unroll
            for (int nf = 0; nf < 3; ++nf)
                kv[mf][nf] = __builtin_amdgcn_mfma_f32_16x16x32_bf16(afr[mf], bfr[nf], kv[mf][nf], 0, 0, 0);
    }

    #pragma unroll
    for (int mf = 0; mf < 3; ++mf) {
        float s = ksum_p[mf];
        s += __shfl_xor(s, 16);
        s += __shfl_xor(s, 32);
        if (kq == 0) KsumS[wid][mf * 16 + c16] = s;
    }

    #pragma unroll
    for (int mf = 0; mf < 3; ++mf) {
        #pragma unroll
        for (int nf = 0; nf < 3; ++nf) {
            const int dv = nf * 16 + c16;
            const int d0 = (mf * 16 + kq * 4) ^ ((dv & 7) << 3);
            uint2 w;
            w.x = f2bf(kv[mf][nf][0]) | (f2bf(kv[mf][nf][1]) << 16);
            w.y = f2bf(kv[mf][nf][2]) | (f2bf(kv[mf][nf][3]) << 16);
            *(uint2*)&KVt[wid][dv][d0] = w;
        }
    }

    s16x8 qf[6][2];
    const s16x8 zfrag = {0, 0, 0, 0, 0, 0, 0, 0};
    #pragma unroll
    for (int mf = 0; mf < 6; ++mf) {
        const int l = mf * 16 + c16;
        float dsum = 0.f;
        #pragma unroll
        for (int ks = 0; ks < 2; ++ks) {
            if (ks == 0 || kq < 2) {
                const int d = ks * 32 + khalf;
                union { unsigned short us[8]; s16x8 v; } pk;
                pk.v = *(const s16x8*)&qb[base + (long)l * ld + d];
                #pragma unroll
                for (int j = 0; j < 8; ++j)
                    dsum += bf2f(pk.us[j]) * KsumS[wid][d + j];
                qf[mf][ks] = pk.v;
            } else {
                qf[mf][ks] = zfrag;
            }
        }
        dsum += __shfl_xor(dsum, 16);
        dsum += __shfl_xor(dsum, 32);
        if (kq == 0) ZlS[wid][l] = 1.f / (dsum + 1e-6f);
    }

    #pragma unroll
    for (int nf = 0; nf < 3; ++nf) {
        const int dv = nf * 16 + c16;
        const int sw = (dv & 7) << 3;
        const s16x8 b0 = *(const s16x8*)&KVt[wid][dv][khalf ^ sw];
        const s16x8 b1 = *(const s16x8*)&KVt[wid][dv][(32 + khalf) ^ sw];
        #pragma unroll
        for (int mf = 0; mf < 6; ++mf) {
            f32x4 a = {};
            a = __builtin_amdgcn_mfma_f32_16x16x32_bf16(qf[mf][0], b0, a, 0, 0, 0);
            a = __builtin_amdgcn_mfma_f32_16x16x32_bf16(qf[mf][1], b1, a, 0, 0, 0);
            const int lb = mf * 16 + kq * 4;
            const long rbase = baseo + (long)lb * ldo + dv;
            #pragma unroll
            for (int rr = 0; rr < 4; ++rr) {
                const float z = ZlS[wid][lb + rr];
                ob[rbase + (long)rr * ldo] = (unsigned short)f2bf(a[rr] * z);
            }
        }
    }
}

// d/w heads: one wave per row; 4 simultaneous 384-dots, shfl reduce.
__global__ __launch_bounds__(256)
void head_kernel(const float* __restrict__ net,
                 const float* __restrict__ Wd, const float* __restrict__ bd,
                 const float* __restrict__ Ww, const float* __restrict__ bw,
                 float* __restrict__ dout, float* __restrict__ wout)
{
    const int wave = threadIdx.x >> 6;
    const int lane = threadIdx.x & 63;
    const long row = (long)blockIdx.x * 4 + wave;
    const float* p = net + row * DIMV;
    float a0 = 0.f, a1 = 0.f, a2 = 0.f, a3 = 0.f;
    #pragma unroll
    for (int i = 0; i < 6; ++i) {
        int c = lane + i * 64;
        float r = fmaxf(p[c], 0.f);
        a0 = fmaf(r, Wd[c * 2 + 0], a0);
        a1 = fmaf(r, Wd[c * 2 + 1], a1);
        a2 = fmaf(r, Ww[c * 2 + 0], a2);
        a3 = fmaf(r, Ww[c * 2 + 1], a3);
    }
    #pragma unroll
    for (int o = 32; o > 0; o >>= 1) {
        a0 += __shfl_xor(a0, o);
        a1 += __shfl_xor(a1, o);
        a2 += __shfl_xor(a2, o);
        a3 += __shfl_xor(a3, o);
    }
    if (lane == 0) {
        dout[row * 2 + 0] = a0 + bd[0];
        dout[row * 2 + 1] = a1 + bd[1];
        wout[row * 2 + 0] = 1.f / (1.f + expf(-(a2 + bw[0])));
        wout[row * 2 + 1] = 1.f / (1.f + expf(-(a3 + bw[1])));
    }
}

extern "C" void kernel_launch(void* const* d_in, const int* in_sizes, int n_in,
                              void* d_out, int out_size, void* d_ws, size_t ws_size,
                              hipStream_t stream)
{
    const float* net_in = (const float*)d_in[0];
    const float* inp    = (const float*)d_in[1];
    const float* corr   = (const float*)d_in[2];
    const float* posenc = (const float*)d_in[4];
    const int*   ix     = (const int*)d_in[8];
    const int*   jx     = (const int*)d_in[9];
    const int*   flat   = (const int*)d_in[10];

    const float* Wc1 = (const float*)d_in[11]; const float* bc1 = (const float*)d_in[12];
    const float* Wc2 = (const float*)d_in[13]; const float* bc2 = (const float*)d_in[14];
    const float* g_lnc = (const float*)d_in[15]; const float* b_lnc = (const float*)d_in[16];
    const float* Wc3 = (const float*)d_in[17]; const float* bc3 = (const float*)d_in[18];
    const float* g_norm = (const float*)d_in[19]; const float* b_norm = (const float*)d_in[20];
    const float* W1a = (const float*)d_in[21]; const float* b1a = (const float*)d_in[22];
    const float* W1b = (const float*)d_in[23]; const float* b1b = (const float*)d_in[24];
    const float* W2a = (const float*)d_in[25]; const float* b2a = (const float*)d_in[26];
    const float* W2b = (const float*)d_in[27]; const float* b2b = (const float*)d_in[28];
    const float* Wf = (const float*)d_in[29]; const float* bff = (const float*)d_in[30];
    const float* Wg = (const float*)d_in[31]; const float* bg = (const float*)d_in[32];
    const float* Wh = (const float*)d_in[33]; const float* bh = (const float*)d_in[34];
    const float* g_norm2 = (const float*)d_in[35]; const float* b_norm2 = (const float*)d_in[36];
    const float* Wq = (const float*)d_in[37]; const float* bq = (const float*)d_in[38];
    const float* Wk = (const float*)d_in[39]; const float* bk = (const float*)d_in[40];
    const float* Wv = (const float*)d_in[41]; const float* bv = (const float*)d_in[42];
    const float* Wm = (const float*)d_in[43]; const float* bm = (const float*)d_in[44];
    const float* Wgt = (const float*)d_in[45]; const float* bgt = (const float*)d_in[46];
    const float* Wd = (const float*)d_in[47]; const float* bd = (const float*)d_in[48];
    const float* Ww = (const float*)d_in[49]; const float* bw = (const float*)d_in[50];

    // ---- workspace layout ----
    const size_t EB  = (size_t)ETOK * DIMV;
    const size_t WSLOT = (size_t)DIMV * DIMV;
    char* p = (char*)d_ws;
    float* Y2f = (float*)p;           p += (size_t)NPATCHV * DIMV * 4;
    unsigned short* WT = (unsigned short*)p;
    p += (13 * WSLOT + (size_t)DIMV * CORR_PAD + (size_t)DIMV * 768) * 2;
    unsigned short* ZR  = (unsigned short*)p; p += 4096;
    float* bqkv = (float*)p;          p += 1152 * 4;
    float* bgf  = (float*)p;          p += 768 * 4;
    unsigned short* Cb0 = (unsigned short*)p; p += EB * 2;
    unsigned short* Bb  = (unsigned short*)p; p += EB * 2;
    unsigned short* Xb1 = (unsigned short*)p; p += EB * 2;
    unsigned short* Xb2 = (unsigned short*)p; p += EB * 2;
    unsigned short* Xgf = (unsigned short*)p; p += (size_t)ETOK * 768 * 2;
    unsigned short* TM  = (unsigned short*)p; p += (size_t)ETOK * 768 * 2;
    unsigned short* Yb  = (unsigned short*)p; p += (size_t)NPATCHV * DIMV * 2;
    unsigned short* QKV = (unsigned short*)p; p += (size_t)ETOK * 1152 * 2;
    unsigned short* corrb = QKV;   // overlay: corrb (99MB) over QKV (127MB)

    unsigned short* Wc2t = WT + 0 * WSLOT;
    unsigned short* Wc3t = WT + 1 * WSLOT;
    unsigned short* W1at = WT + 2 * WSLOT;
    unsigned short* W1bt = WT + 3 * WSLOT;
    unsigned short* W2at = WT + 4 * WSLOT;
    unsigned short* W2bt = WT + 5 * WSLOT;
    unsigned short* WgfT = WT + 6 * WSLOT;   // [768][384]: Wg | Wf
    unsigned short* Wht  = WT + 8 * WSLOT;
    unsigned short* Wqkv = WT + 9 * WSLOT;   // [1152][384]: Wq | Wk | Wv
    unsigned short* Wmt  = WT + 12 * WSLOT;
    unsigned short* Wc1t = WT + 13 * WSLOT;                 // [384][896]
    unsigned short* Wgtt = Wc1t + (size_t)DIMV * CORR_PAD;  // [384][768]

    float* out_net = (float*)d_out;
    float* out_d = out_net + EB;
    float* out_w = out_d + (size_t)ETOK * 2;

    const dim3 gB(DIMV / 128, ETOK / 128);      // (3, 432)
    const dim3 gGF(768 / 128, ETOK / 128);      // (6, 432)
    const dim3 gQKV(1152 / 128, ETOK / 128);    // (9, 432)
    const dim3 gY(DIMV / 128, NPATCHV / 128);   // (3, 18)
    const int lnBlocks = ETOK / 4;

    // ---- pre-passes ----
    {
        const long tot = (long)ETOK * (CORR_PAD / 2);
        corrconv<<<(int)((tot + 255) / 256), 256, 0, stream>>>(corr, (unsigned int*)corrb, (unsigned int*)ZR);
    }
    {
        WPtrs13 w;
        w.p[0] = Wc2; w.p[1] = Wc3; w.p[2] = W1a; w.p[3] = W1b; w.p[4] = W2a;
        w.p[5] = W2b; w.p[6] = Wg;  w.p[7] = Wf;  w.p[8] = Wh;  w.p[9] = Wq;
        w.p[10] = Wk; w.p[11] = Wv; w.p[12] = Wm;
        wtrans13<<<dim3(12, 12, 13), dim3(32, 8), 0, stream>>>(w, WT);
        wtransb<<<dim3(28, 12), dim3(32, 8), 0, stream>>>(Wc1, Wc1t, CORR_DIMV, CORR_PAD);
        wtransb<<<dim3(24, 12), dim3(32, 8), 0, stream>>>(Wgt, Wgtt, 768, 768);
        biascat<<<5, 256, 0, stream>>>(bq, bk, bv, bg, bff, bqkv, bgf);
    }

    // corr encoder
    gemm_bb<1, false><<<gB, 256, 0, stream>>>(corrb, CORR_PAD, Wc1t, bc1, nullptr, Cb0, DIMV, 0, nullptr, ZR, CORR_PAD);
    gemm_bb<5, false><<<gB, 256, 0, stream>>>(Cb0, DIMV, Wc2t, bc2, nullptr, Xb1, DIMV, 0, nullptr, ZR, DIMV);
    ln_kernel<0, true><<<lnBlocks, 256, 0, stream>>>(Cb0, DIMV, nullptr, nullptr, Xb1, nullptr, nullptr, g_lnc, b_lnc);
    gemm_bb<5, false><<<gB, 256, 0, stream>>>(Cb0, DIMV, Wc3t, bc3, nullptr, Xb2, DIMV, 0, nullptr, ZR, DIMV);

    // net = LN(net + inp + c) -> Bb (bf16)
    ln_kernel<1, false><<<lnBlocks, 256, 0, stream>>>(Bb, DIMV, net_in, inp, Xb2, nullptr, nullptr, g_norm, b_norm);

    // net += mlp2(mask_ix * net[ix])
    gemm_bb<1, true><<<gB, 256, 0, stream>>>(Bb, DIMV, W1at, b1a, nullptr, Cb0, DIMV, 0, ix, ZR, DIMV);
    gemm_bb<6, false><<<gB, 256, 0, stream>>>(Cb0, DIMV, W1bt, b1b, nullptr, Bb, DIMV, 0, nullptr, ZR, DIMV);

    // net += mlp2(mask_jx * net[jx])
    gemm_bb<1, true><<<gB, 256, 0, stream>>>(Bb, DIMV, W2at, b2a, nullptr, Cb0, DIMV, 0, jx, ZR, DIMV);
    gemm_bb<6, false><<<gB, 256, 0, stream>>>(Cb0, DIMV, W2bt, b2b, nullptr, Bb, DIMV, 0, nullptr, ZR, DIMV);

    // soft aggregation: g|f in one N=768 GEMM
    gemm_bb<5, false><<<gGF, 256, 0, stream>>>(Bb, DIMV, WgfT, bgf, nullptr, Xgf, 768, 0, nullptr, ZR, DIMV);
    softagg_kernel<<<NPATCHV, 384, 0, stream>>>(Xgf, Yb);
    gemm_bb<0, false><<<gY, 256, 0, stream>>>(Yb, DIMV, Wht, bh, Y2f, nullptr, DIMV, 0, nullptr, ZR, DIMV);

    // tokens = LN(net[flat] + Y2[flat/24]) -> TM[:, 0:384] bf16
    ln_kernel<2, false><<<lnBlocks, 256, 0, stream>>>(TM, 768, nullptr, nullptr, Bb, Y2f, flat, g_norm2, b_norm2);

    // q|k|v in one N=1152 GEMM -> QKV [E][1152]
    gemm_bb<5, false><<<gQKV, 256, 0, stream>>>(TM, 768, Wqkv, bqkv, nullptr, QKV, 1152, 0, nullptr, ZR, DIMV);

    // RoPE + elu+1 on q,k (bf16 in place)
    rope_kernel<<<(int)((long)ETOK * 48 / 256), 256, 0, stream>>>(QKV, QKV + 384, 1152, posenc, flat);

    // linear attention -> Cb0 (bf16)
    attn_kernel<<<NGRP * NHEADV / 4, 256, 0, stream>>>(QKV, QKV + 384, QKV + 768, 1152, Cb0, DIMV);

    // msg = out @ Wm + bm -> TM[:, 384:768] bf16
    gemm_bb<5, false><<<gB, 256, 0, stream>>>(Cb0, DIMV, Wmt, bm, nullptr, TM, 768, 384, nullptr, ZR, DIMV);

    // gate+combine: out_net[flat[e]] = tok + sigmoid(TM @ Wgt + bgt) * msg
    gemm_bb<7, false><<<gB, 256, 0, stream>>>(TM, 768, Wgtt, bgt, out_net, TM, 768, 384, flat, ZR, 768);

    // heads
    head_kernel<<<lnBlocks, 256, 0, stream>>>(out_net, Wd, bd, Ww, bw, out_d, out_w);
}